// Round 6
// baseline (203.341 us; speedup 1.0000x reference)
//
#include <hip/hip_runtime.h>
#include <hip/hip_bf16.h>

typedef __attribute__((ext_vector_type(8))) short bf16x8;
typedef __attribute__((ext_vector_type(4))) float f32x4;

#define LOG2E 1.44269504088896f

extern "C" __device__ float __ocml_native_exp2_f32(float);   // raw v_exp_f32

__device__ __forceinline__ unsigned short f2bf(float f) {
    union { float f; unsigned int u; } v; v.f = f;
    unsigned int r = v.u + 0x7FFF + ((v.u >> 16) & 1);   // RNE to bf16
    return (unsigned short)(r >> 16);
}

// gfx950 packed f32x2 -> bf16x2 (RNE), one VALU inst
__device__ __forceinline__ unsigned int pk_bf16(float lo, float hi) {
    unsigned int r;
    asm("v_cvt_pk_bf16_f32 %0, %1, %2" : "=v"(r) : "v"(lo), "v"(hi));
    return r;
}

typedef __attribute__((address_space(3))) unsigned int lds_uint;
typedef __attribute__((address_space(1))) const unsigned int glob_uint;
__device__ __forceinline__ void gl2lds16(const void* g, void* l) {
    __builtin_amdgcn_global_load_lds((glob_uint*)g, (lds_uint*)l, 16, 0, 0);
}

#define VMW(n) asm volatile("s_waitcnt vmcnt(" #n ")" ::: "memory")

// vmcnt(N) + lgkmcnt(0) + barrier (gemm_core pipeline sync)
#define SYNC(vm)                                                             \
    asm volatile("s_waitcnt vmcnt(" #vm ")\n\ts_waitcnt lgkmcnt(0)" ::: "memory"); \
    __builtin_amdgcn_s_barrier();                                            \
    asm volatile("" ::: "memory")

// lgkm drain + barrier (flash K-buffer rotation, once per 2 tiles)
#define SYNCB                                                                \
    asm volatile("s_waitcnt lgkmcnt(0)" ::: "memory");                       \
    __builtin_amdgcn_s_barrier();                                            \
    asm volatile("" ::: "memory")

// ---------------------------------------------------------------- utilities
__global__ __launch_bounds__(256) void cvt_bf16(const float* __restrict__ in,
                                                unsigned int* __restrict__ out, int n4) {
    int i = blockIdx.x * 256 + threadIdx.x;
    if (i >= n4) return;
    float4 v = ((const float4*)in)[i];
    uint2 o;
    o.x = pk_bf16(v.x, v.y);
    o.y = pk_bf16(v.z, v.w);
    ((uint2*)out)[i] = o;
}

// 4 fused 1024x1024 fp32->bf16 transposes, z selects which weight
__global__ __launch_bounds__(256) void transpose4_bf16(
    const float* __restrict__ w0, const float* __restrict__ w1,
    const float* __restrict__ w2, const float* __restrict__ w3,
    unsigned short* __restrict__ o0, unsigned short* __restrict__ o1,
    unsigned short* __restrict__ o2, unsigned short* __restrict__ o3) {
    const int z = blockIdx.z;
    const float* in = (z == 0) ? w0 : (z == 1) ? w1 : (z == 2) ? w2 : w3;
    unsigned short* out = (z == 0) ? o0 : (z == 1) ? o1 : (z == 2) ? o2 : o3;
    __shared__ float t[32][33];
    int tx = threadIdx.x & 31, ty = threadIdx.x >> 5;
    int r0 = blockIdx.y * 32, c0 = blockIdx.x * 32;
    for (int i = 0; i < 32; i += 8)
        t[ty + i][tx] = in[(size_t)(r0 + ty + i) * 1024 + c0 + tx];
    __syncthreads();
    for (int i = 0; i < 32; i += 8)
        out[(size_t)(c0 + ty + i) * 1024 + r0 + tx] = f2bf(t[tx][ty + i]);
}

// ---------------------------------------------------------------- GEMM core
// C[128x128] = A[128xK] * BT[128xK]^T ; 256 thr, 4 waves each 64x64.
// 3-buffer LDS pipeline + register double-buffered fragments (R4 form).
__device__ __forceinline__ void gemm_core(const short* __restrict__ A,
                                          const short* __restrict__ BT,
                                          int K, int bm0, int bn0,
                                          short* sm, f32x4 acc[4][4]) {
    const int tid = threadIdx.x;
    const int lane = tid & 63;
    const int w = tid >> 6;
    const int wr0 = (w >> 1) * 64;
    const int wc0 = (w & 1) * 64;
    const int l15 = lane & 15, quad = lane >> 4;
    const int sr = lane >> 2;                              // staging row in 16-row chunk
    const int slog = (lane & 3) ^ (sr & 3) ^ (sr >> 2);    // swizzled k-chunk to fetch

#pragma unroll
    for (int i = 0; i < 4; i++)
#pragma unroll
        for (int j = 0; j < 4; j++) acc[i][j] = (f32x4)0.f;

    const short* sp[4];
    int sdo[4];
#pragma unroll
    for (int i = 0; i < 4; i++) {
        int c = w * 4 + i;
        sp[i] = (c < 8) ? A + (size_t)(bm0 + c * 16 + sr) * K + slog * 8
                        : BT + (size_t)(bn0 + (c - 8) * 16 + sr) * K + slog * 8;
        sdo[i] = c * 512;
    }
    auto stage = [&](int buf) {
        short* bb = sm + buf * 8192;
#pragma unroll
        for (int i = 0; i < 4; i++) {
            gl2lds16(sp[i], bb + sdo[i]);
            sp[i] += 32;
        }
    };
    const int ph = (quad ^ (l15 & 3) ^ (l15 >> 2)) * 8;
    auto loadf = [&](bf16x8* af, bf16x8* bfr, int buf) {
        const short* Ab = sm + buf * 8192;
        const short* Bb = Ab + 4096;
#pragma unroll
        for (int im = 0; im < 4; im++)
            af[im] = *(const bf16x8*)&Ab[(wr0 + im * 16 + l15) * 32 + ph];
#pragma unroll
        for (int in = 0; in < 4; in++)
            bfr[in] = *(const bf16x8*)&Bb[(wc0 + in * 16 + l15) * 32 + ph];
        __builtin_amdgcn_sched_barrier(0);   // pin reads here (issue-early)
    };
    auto computef = [&](const bf16x8* af, const bf16x8* bfr) {
        __builtin_amdgcn_s_setprio(1);
#pragma unroll
        for (int im = 0; im < 4; im++)
#pragma unroll
            for (int in = 0; in < 4; in++)
                acc[im][in] = __builtin_amdgcn_mfma_f32_16x16x32_bf16(af[im], bfr[in], acc[im][in], 0, 0, 0);
        __builtin_amdgcn_s_setprio(0);
    };

    stage(0); stage(1);
    asm volatile("s_waitcnt vmcnt(4)" ::: "memory");   // tile 0 resident
    __builtin_amdgcn_s_barrier();
    asm volatile("" ::: "memory");

    bf16x8 aA[4], bA[4], aB[4], bB[4];
    loadf(aA, bA, 0);

    const int nt = K >> 5;                 // 32 K-steps of 32
    int bs = 2, rb = 1;
    for (int t = 0; t < nt - 2; t += 2) {
        stage(bs); bs = (bs == 2) ? 0 : bs + 1;
        SYNC(4);                                   // tile t+1 resident
        loadf(aB, bB, rb); rb = (rb == 2) ? 0 : rb + 1;
        computef(aA, bA);                          // tile t
        stage(bs); bs = (bs == 2) ? 0 : bs + 1;
        SYNC(4);                                   // tile t+2 resident
        loadf(aA, bA, rb); rb = (rb == 2) ? 0 : rb + 1;
        computef(aB, bB);                          // tile t+1
    }
    SYNC(0);                                       // tile nt-1 resident
    loadf(aB, bB, rb);
    computef(aA, bA);                              // tile nt-2
    computef(aB, bB);                              // tile nt-1
}

// QKV projection.
__global__ __launch_bounds__(256, 3) void gemm_qkv(
    const short* __restrict__ xb,
    const short* __restrict__ wqT, const short* __restrict__ wkT, const short* __restrict__ wvT,
    const float* __restrict__ bq, const float* __restrict__ bk, const float* __restrict__ bv,
    unsigned short* __restrict__ qb, unsigned short* __restrict__ kb, unsigned short* __restrict__ vTb) {
    __shared__ short sm[24576];            // 3 x (A 4096 + B 4096) = 48KB
    const int z = blockIdx.z;
    const short* Amat = (z == 2) ? wvT : xb;
    const short* Bmat = (z == 0) ? wqT : (z == 1) ? wkT : xb;
    const float* bias = (z == 0) ? bq : (z == 1) ? bk : bv;
    const float scl = (z == 0) ? 0.125f * LOG2E : 1.f;
    const int bm0 = (z == 2) ? blockIdx.y * 128 : blockIdx.x * 128;
    const int bn0 = (z == 2) ? blockIdx.x * 128 : blockIdx.y * 128;
    f32x4 acc[4][4];
    gemm_core(Amat, Bmat, 1024, bm0, bn0, sm, acc);
    const int lane = threadIdx.x & 63, w = threadIdx.x >> 6;
    const int wr0 = (w >> 1) * 64, wc0 = (w & 1) * 64, l15 = lane & 15, quad = lane >> 4;
    if (z == 2) {
        for (int im = 0; im < 4; im++)
            for (int in = 0; in < 4; in++)
                for (int r = 0; r < 4; r++) {
                    int rowa = bm0 + wr0 + im * 16 + quad * 4 + r;   // h*64+a
                    int colg = bn0 + wc0 + in * 16 + l15;            // b*2048+s
                    unsigned short ov = f2bf(acc[im][in][r] + bias[rowa]);
                    int b = colg >> 11, s = colg & 2047;
                    vTb[(size_t)b * 2097152 + (size_t)rowa * 2048 + s] = ov;
                }
    } else {
        for (int im = 0; im < 4; im++)
            for (int in = 0; in < 4; in++)
                for (int r = 0; r < 4; r++) {
                    int rowg = bm0 + wr0 + im * 16 + quad * 4 + r;   // b*2048+s
                    int colg = bn0 + wc0 + in * 16 + l15;            // h*64+a
                    unsigned short ov = f2bf((acc[im][in][r] + bias[colg]) * scl);
                    int b = rowg >> 11, s = rowg & 2047;
                    int h = colg >> 6, a = colg & 63;
                    int bh = b * 16 + h;
                    if (z == 0) qb[((size_t)bh * 2048 + s) * 64 + a] = ov;
                    else        kb[((size_t)bh * 2048 + s) * 64 + a] = ov;
                }
    }
}

__global__ __launch_bounds__(256, 3) void gemm_out(
    const short* __restrict__ att, const short* __restrict__ woT,
    const float* __restrict__ bo, float* __restrict__ out) {
    __shared__ short sm[24576];
    const int bm0 = blockIdx.x * 128, bn0 = blockIdx.y * 128;
    f32x4 acc[4][4];
    gemm_core(att, woT, 1024, bm0, bn0, sm, acc);
    const int lane = threadIdx.x & 63, w = threadIdx.x >> 6;
    const int wr0 = (w >> 1) * 64, wc0 = (w & 1) * 64, l15 = lane & 15, quad = lane >> 4;
    for (int im = 0; im < 4; im++)
        for (int in = 0; in < 4; in++)
            for (int r = 0; r < 4; r++) {
                int rowg = bm0 + wr0 + im * 16 + quad * 4 + r;
                int colg = bn0 + wc0 + in * 16 + l15;
                out[(size_t)rowg * 1024 + colg] = acc[im][in][r] + bo[colg];
            }
}

// ---------------------------------------------------------------- flash attn
// 1D grid 512 (XCD-swizzled); 256 thr = 4 waves, each owns 32 q-cols.
// BKV=64, HD=64. S^T = K*Q^T, O^T = V^T*P^T; softmax w/o max-subtraction.
//
// V NEVER TOUCHES LDS: PV fragments are 16B-contiguous rows of vTb, loaded
// straight from global (L2-resident via XCD swizzle) into registers with
// depth-1 prefetch (issued step t, consumed by PV(t) at step t+1). This
// halves LDS traffic (the measured wall) and shifts it to the 5.7%-used
// L2 path. K stays LDS-staged (4x reuse across waves): 6 buffers of 8KB,
// all 4 waves stage (2 gl2lds/tile), barrier only once per 2 tiles.
// Manual vmcnt guards only gl2lds->ds_read residency:
//   steady FIFO at kf read = [st(t+1),st(t+2),vf(t-1),st(t+3)] = 14 -> vmcnt(12)
//   tail (staging stopped): vmcnt(10), vmcnt(8). Compiler tracks vf/Q loads.
// Step t: [vmcnt | ds_read kf(t+1) | PV(t-1) (waits vf(t-1)) | issue vf(t)
//          | QK(t) | smax->bp(t) | stage K(t+4)] ; SYNCB after odd steps.
__global__ __launch_bounds__(256, 2) void flash_attn(
    const unsigned short* __restrict__ qb, const unsigned short* __restrict__ kb,
    const unsigned short* __restrict__ vTb, unsigned short* __restrict__ att) {
    __shared__ short Ks[6][4096];              // 48KB: 6 K tiles of 64x64
    const int tid = threadIdx.x, lane = tid & 63, w = tid >> 6;
    const int l15 = lane & 15, quad = lane >> 4;
    const int lid = ((blockIdx.x & 7) << 6) | (blockIdx.x >> 3);   // XCD swizzle
    const int q0 = (lid & 15) * 128;
    const int bh = lid >> 4;
    const size_t qkbase = (size_t)bh * 2048 * 64;
    const size_t vbase = (size_t)bh * 64 * 2048;
    const int sr = lane >> 3;                  // staging row (8 rows / 1KB call)
    const int slog = (lane & 7) ^ sr;          // swizzled chunk to fetch
    const int l7 = l15 & 7;

    // K staging: all 4 waves, wave w owns rows w*16..w*16+15 (2 x 1KB / tile)
    const unsigned short* sgp = kb + qkbase + (size_t)(w * 16 + sr) * 64 + slog * 8;
    short* sgb = &Ks[0][0] + w * 1024;
    auto stage_tile = [&](int buf) {
        short* sd = sgb + buf * 4096;
        gl2lds16(sgp, sd);
        gl2lds16(sgp + 512, sd + 512);
        sgp += 4096;                           // next kv tile: +64 rows
    };

    const int wq0 = w * 32;
    const int c0 = (quad ^ l7) * 8, c1 = c0 ^ 32;   // swizzled d-chunk offsets (LDS)
    const int fb = l15 * 64;                        // fragment row base

    // Q fragments direct from global (B-operand layout: row=l15, k=quad*8+j)
    const unsigned short* qrow = qb + qkbase + (size_t)(q0 + wq0 + l15) * 64 + quad * 8;
    bf16x8 aq00 = *(const bf16x8*)qrow;
    bf16x8 aq01 = *(const bf16x8*)(qrow + 32);
    bf16x8 aq10 = *(const bf16x8*)(qrow + 1024);
    bf16x8 aq11 = *(const bf16x8*)(qrow + 1024 + 32);

    // V fragments direct from global: lane reads vTb[a=dt*16+l15][kv0+quad*8(+32)]
    const unsigned short* vp = vTb + vbase + (size_t)l15 * 2048 + quad * 8;
    int kvo = 0;
    bf16x8 vf[8];                                   // single bank, depth-1
    auto load_vf = [&] {
#pragma unroll
        for (int dt = 0; dt < 4; dt++) {
            vf[2 * dt]     = *(const bf16x8*)(vp + (size_t)dt * 32768 + kvo);
            vf[2 * dt + 1] = *(const bf16x8*)(vp + (size_t)dt * 32768 + kvo + 32);
        }
        kvo += 64;
    };

    auto load_kf = [&](bf16x8* kf, int buf) {
        const short* Kb = &Ks[0][0] + buf * 4096;
#pragma unroll
        for (int t = 0; t < 4; t++) {
            kf[2 * t]     = *(const bf16x8*)(Kb + fb + c0 + t * 1024);
            kf[2 * t + 1] = *(const bf16x8*)(Kb + fb + c1 + t * 1024);
        }
        __builtin_amdgcn_sched_barrier(0);     // pin ds_reads early
    };

    f32x4 o0[4], o1[4];
#pragma unroll
    for (int dt = 0; dt < 4; dt++) { o0[dt] = (f32x4)0.f; o1[dt] = (f32x4)0.f; }
    f32x4 ls0 = (f32x4)0.f, ls1 = (f32x4)0.f;

    auto qk = [&](const bf16x8* kf, f32x4* sc0, f32x4* sc1) {
        __builtin_amdgcn_s_setprio(1);
#pragma unroll
        for (int t = 0; t < 4; t++) {
            sc0[t] = __builtin_amdgcn_mfma_f32_16x16x32_bf16(kf[2 * t], aq00, (f32x4)0.f, 0, 0, 0);
            sc1[t] = __builtin_amdgcn_mfma_f32_16x16x32_bf16(kf[2 * t], aq10, (f32x4)0.f, 0, 0, 0);
        }
#pragma unroll
        for (int t = 0; t < 4; t++) {
            sc0[t] = __builtin_amdgcn_mfma_f32_16x16x32_bf16(kf[2 * t + 1], aq01, sc0[t], 0, 0, 0);
            sc1[t] = __builtin_amdgcn_mfma_f32_16x16x32_bf16(kf[2 * t + 1], aq11, sc1[t], 0, 0, 0);
        }
        __builtin_amdgcn_s_setprio(0);
    };

    // exp2 + row-sum + in-register P transpose (C-frag -> PV B-frag)
    auto smax = [&](f32x4 (&sc)[4], f32x4& lsr, bf16x8* bp) {
#pragma unroll
        for (int t = 0; t < 4; t++) {
#pragma unroll
            for (int r = 0; r < 4; r++) sc[t][r] = __ocml_native_exp2_f32(sc[t][r]);
            lsr += sc[t];
        }
#pragma unroll
        for (int t2 = 0; t2 < 2; t2++) {
            unsigned pa = pk_bf16(sc[2 * t2][0], sc[2 * t2][1]);
            unsigned pb = pk_bf16(sc[2 * t2][2], sc[2 * t2][3]);
            unsigned pc = pk_bf16(sc[2 * t2 + 1][0], sc[2 * t2 + 1][1]);
            unsigned pd = pk_bf16(sc[2 * t2 + 1][2], sc[2 * t2 + 1][3]);
            asm("v_permlane32_swap_b32 %0, %1" : "+v"(pa), "+v"(pc));
            asm("v_permlane32_swap_b32 %0, %1" : "+v"(pb), "+v"(pd));
            asm("v_permlane16_swap_b32 %0, %1" : "+v"(pa), "+v"(pc));
            asm("v_permlane16_swap_b32 %0, %1" : "+v"(pb), "+v"(pd));
            union { unsigned u[4]; bf16x8 v; } cvt;
            cvt.u[0] = pa; cvt.u[1] = pb; cvt.u[2] = pc; cvt.u[3] = pd;
            bp[t2] = cvt.v;
        }
    };

    auto pv = [&](const bf16x8* bp) {          // PV from bp bank + current vf
        __builtin_amdgcn_s_setprio(1);
#pragma unroll
        for (int t2 = 0; t2 < 2; t2++)
#pragma unroll
            for (int dt = 0; dt < 4; dt++) {
                o0[dt] = __builtin_amdgcn_mfma_f32_16x16x32_bf16(vf[2 * dt + t2], bp[t2], o0[dt], 0, 0, 0);
                o1[dt] = __builtin_amdgcn_mfma_f32_16x16x32_bf16(vf[2 * dt + t2], bp[2 + t2], o1[dt], 0, 0, 0);
            }
        __builtin_amdgcn_s_setprio(0);
    };

    bf16x8 kfA[8], kfB[8];
    bf16x8 bpA[4], bpB[4];

    // step t: kfC = frags(t), loads kfN <- tile t+1, writes bpC = bp(t),
    // PV(t-1) from bpP + vf (holding tile t-1), then vf <- tile t.
    auto step = [&](bf16x8* kfC, bf16x8* kfN, bf16x8* bpC, const bf16x8* bpP,
                    int nbuf, bool dokf, bool dopv, bool dostage, int sbuf) {
        if (dokf) load_kf(kfN, nbuf);
        if (dopv) pv(bpP);                     // compiler inserts vmcnt for vf
        load_vf();
        f32x4 sc0[4], sc1[4];
        qk(kfC, sc0, sc1);
        smax(sc0, ls0, bpA == bpC ? bpA : bpB);   // bpC (kept static-friendly)
        smax(sc1, ls1, (bpA == bpC ? bpA : bpB) + 2);
        if (dostage) stage_tile(sbuf);
    };

    // prologue: stage tiles 0-3; tiles 0,1 resident before loop
    stage_tile(0); stage_tile(1); stage_tile(2); stage_tile(3);
    VMW(4);
    __builtin_amdgcn_s_barrier();
    asm volatile("" ::: "memory");
    load_kf(kfA, 0);

    VMW(12); step(kfA, kfB, bpA, bpB, 1, true, false, true, 4);   // t=0
    VMW(12); step(kfB, kfA, bpB, bpA, 2, true, true,  true, 5);   // t=1
    SYNCB;
    int nb = 3, sb = 0;
    for (int it = 0; it < 13; it++) {                             // t=2..27
        VMW(12); step(kfA, kfB, bpA, bpB, nb, true, true, true, sb);
        nb = (nb == 5) ? 0 : nb + 1; sb = (sb == 5) ? 0 : sb + 1;
        VMW(12); step(kfB, kfA, bpB, bpA, nb, true, true, true, sb);
        nb = (nb == 5) ? 0 : nb + 1; sb = (sb == 5) ? 0 : sb + 1;
        SYNCB;
    }
    VMW(12); step(kfA, kfB, bpA, bpB, nb, true, true, false, 0);  // t=28
    nb = (nb == 5) ? 0 : nb + 1;
    VMW(10); step(kfB, kfA, bpB, bpA, nb, true, true, false, 0);  // t=29
    nb = (nb == 5) ? 0 : nb + 1;
    VMW(8);  step(kfA, kfB, bpA, bpB, nb, true, true, false, 0);  // t=30
    step(kfB, kfA, bpB, bpA, 0, false, true, false, 0);           // t=31 (PV(30))
    pv(bpB);                                                      // PV(31)

    const int b = bh >> 4, h = bh & 15;
    float l0 = (ls0[0] + ls0[1]) + (ls0[2] + ls0[3]);
    l0 += __shfl_xor(l0, 16);
    l0 += __shfl_xor(l0, 32);
    float inv0 = 1.f / l0;
    float l1 = (ls1[0] + ls1[1]) + (ls1[2] + ls1[3]);
    l1 += __shfl_xor(l1, 16);
    l1 += __shfl_xor(l1, 32);
    float inv1 = 1.f / l1;
    int s = q0 + wq0 + l15;
#pragma unroll
    for (int dt = 0; dt < 4; dt++) {
        int col = h * 64 + dt * 16 + quad * 4;
        uint2 pk;
        pk.x = pk_bf16(o0[dt][0] * inv0, o0[dt][1] * inv0);
        pk.y = pk_bf16(o0[dt][2] * inv0, o0[dt][3] * inv0);
        *(uint2*)&att[((size_t)b * 2048 + s) * 1024 + col] = pk;
        pk.x = pk_bf16(o1[dt][0] * inv1, o1[dt][1] * inv1);
        pk.y = pk_bf16(o1[dt][2] * inv1, o1[dt][3] * inv1);
        *(uint2*)&att[((size_t)b * 2048 + s + 16) * 1024 + col] = pk;
    }
}

extern "C" void kernel_launch(void* const* d_in, const int* in_sizes, int n_in,
                              void* d_out, int out_size, void* d_ws, size_t ws_size,
                              hipStream_t stream) {
    const float* x  = (const float*)d_in[0];
    const float* Wq = (const float*)d_in[1];
    const float* bq = (const float*)d_in[2];
    const float* Wk = (const float*)d_in[3];
    const float* bk = (const float*)d_in[4];
    const float* Wv = (const float*)d_in[5];
    const float* bv = (const float*)d_in[6];
    const float* Wo = (const float*)d_in[7];
    const float* bo = (const float*)d_in[8];
    float* out = (float*)d_out;

    short* ws  = (short*)d_ws;
    short* xb  = ws;                          // 4M shorts
    short* wqT = ws + 4 * 1024 * 1024;        // 1M each
    short* wkT = wqT + 1024 * 1024;
    short* wvT = wkT + 1024 * 1024;
    short* woT = wvT + 1024 * 1024;
    short* qb  = woT + 1024 * 1024;           // 4M each
    short* kb  = qb + 4 * 1024 * 1024;
    short* vTb = kb + 4 * 1024 * 1024;
    short* att = vTb + 4 * 1024 * 1024;       // total 24M shorts = 48MB

    cvt_bf16<<<4096, 256, 0, stream>>>(x, (unsigned int*)xb, 1024 * 1024);
    transpose4_bf16<<<dim3(32, 32, 4), 256, 0, stream>>>(
        Wq, Wk, Wv, Wo,
        (unsigned short*)wqT, (unsigned short*)wkT,
        (unsigned short*)wvT, (unsigned short*)woT);
    gemm_qkv<<<dim3(32, 8, 3), 256, 0, stream>>>(xb, wqT, wkT, wvT, bq, bk, bv,
                                                 (unsigned short*)qb, (unsigned short*)kb,
                                                 (unsigned short*)vTb);
    flash_attn<<<512, 256, 0, stream>>>((const unsigned short*)qb,
                                        (const unsigned short*)kb,
                                        (const unsigned short*)vTb,
                                        (unsigned short*)att);
    gemm_out<<<dim3(32, 8), 256, 0, stream>>>(att, woT, bo, out);
}

// Round 7
// 190.924 us; speedup vs baseline: 1.0650x; 1.0650x over previous
//
#include <hip/hip_runtime.h>
#include <hip/hip_bf16.h>

typedef __attribute__((ext_vector_type(8))) short bf16x8;
typedef __attribute__((ext_vector_type(4))) float f32x4;

#define LOG2E 1.44269504088896f

extern "C" __device__ float __ocml_native_exp2_f32(float);   // raw v_exp_f32

__device__ __forceinline__ unsigned short f2bf(float f) {
    union { float f; unsigned int u; } v; v.f = f;
    unsigned int r = v.u + 0x7FFF + ((v.u >> 16) & 1);   // RNE to bf16
    return (unsigned short)(r >> 16);
}

// gfx950 packed f32x2 -> bf16x2 (RNE), one VALU inst
__device__ __forceinline__ unsigned int pk_bf16(float lo, float hi) {
    unsigned int r;
    asm("v_cvt_pk_bf16_f32 %0, %1, %2" : "=v"(r) : "v"(lo), "v"(hi));
    return r;
}

typedef __attribute__((address_space(3))) unsigned int lds_uint;
typedef __attribute__((address_space(1))) const unsigned int glob_uint;
__device__ __forceinline__ void gl2lds16(const void* g, void* l) {
    __builtin_amdgcn_global_load_lds((glob_uint*)g, (lds_uint*)l, 16, 0, 0);
}

#define VMW(n) asm volatile("s_waitcnt vmcnt(" #n ")" ::: "memory")

// vmcnt(N) + lgkmcnt(0) + barrier (pipeline sync)
#define SYNC(vm)                                                             \
    asm volatile("s_waitcnt vmcnt(" #vm ")\n\ts_waitcnt lgkmcnt(0)" ::: "memory"); \
    __builtin_amdgcn_s_barrier();                                            \
    asm volatile("" ::: "memory")

// ---------------------------------------------------------------- utilities
__global__ __launch_bounds__(256) void cvt_bf16(const float* __restrict__ in,
                                                unsigned int* __restrict__ out, int n4) {
    int i = blockIdx.x * 256 + threadIdx.x;
    if (i >= n4) return;
    float4 v = ((const float4*)in)[i];
    uint2 o;
    o.x = pk_bf16(v.x, v.y);
    o.y = pk_bf16(v.z, v.w);
    ((uint2*)out)[i] = o;
}

// 4 fused 1024x1024 fp32->bf16 transposes, z selects which weight
__global__ __launch_bounds__(256) void transpose4_bf16(
    const float* __restrict__ w0, const float* __restrict__ w1,
    const float* __restrict__ w2, const float* __restrict__ w3,
    unsigned short* __restrict__ o0, unsigned short* __restrict__ o1,
    unsigned short* __restrict__ o2, unsigned short* __restrict__ o3) {
    const int z = blockIdx.z;
    const float* in = (z == 0) ? w0 : (z == 1) ? w1 : (z == 2) ? w2 : w3;
    unsigned short* out = (z == 0) ? o0 : (z == 1) ? o1 : (z == 2) ? o2 : o3;
    __shared__ float t[32][33];
    int tx = threadIdx.x & 31, ty = threadIdx.x >> 5;
    int r0 = blockIdx.y * 32, c0 = blockIdx.x * 32;
    for (int i = 0; i < 32; i += 8)
        t[ty + i][tx] = in[(size_t)(r0 + ty + i) * 1024 + c0 + tx];
    __syncthreads();
    for (int i = 0; i < 32; i += 8)
        out[(size_t)(c0 + ty + i) * 1024 + r0 + tx] = f2bf(t[tx][ty + i]);
}

// ---------------------------------------------------------------- GEMM core
// C[128x256] = A[128xK] * BT[256xK]^T ; 256 thr, 4 waves in a 2x2 grid,
// each wave owns 64x128 (acc[4][8]). WIDE TILE rationale: the 128x128 core
// was LDS-BW-bound (48KB LDS traffic / 1.05 MFLOP ~= the 128 B/cy port at
// 3 blocks/CU). 128x256 moves 34KB/MFLOP -> MFMA-bound.
// 3-buffer LDS pipeline (24KB each, 72KB total, 2 blocks/CU), depth-2
// prefetch, counted vmcnt: 6 gl2lds per wave per tile -> SYNC(6).
// LDS rows are 32 shorts (4 chunks of 16B); chunk position XOR-swizzled
// by (row&3)^(row>>2) on both store and read sides.
__device__ __forceinline__ void gemm_core(const short* __restrict__ A,
                                          const short* __restrict__ BT,
                                          int K, int bm0, int bn0,
                                          short* sm, f32x4 acc[4][8]) {
    const int tid = threadIdx.x;
    const int lane = tid & 63;
    const int w = tid >> 6;
    const int wr0 = (w >> 1) * 64;
    const int wc0 = (w & 1) * 128;
    const int l15 = lane & 15, quad = lane >> 4;
    const int sr = lane >> 2;                              // staging row in 16-row chunk
    const int slog = (lane & 3) ^ (sr & 3) ^ (sr >> 2);    // swizzled k-chunk to fetch

#pragma unroll
    for (int i = 0; i < 4; i++)
#pragma unroll
        for (int j = 0; j < 8; j++) acc[i][j] = (f32x4)0.f;

    // staging: 24 chunks of 16 rows (A: c<8, B: c>=8); wave w owns 6 chunks
    const short* sp[6];
    int sdo[6];
#pragma unroll
    for (int i = 0; i < 6; i++) {
        int c = w * 6 + i;
        sp[i] = (c < 8) ? A + (size_t)(bm0 + c * 16 + sr) * K + slog * 8
                        : BT + (size_t)(bn0 + (c - 8) * 16 + sr) * K + slog * 8;
        sdo[i] = c * 512;
    }
    auto stage = [&](int buf) {
        short* bb = sm + buf * 12288;
#pragma unroll
        for (int i = 0; i < 6; i++) {
            gl2lds16(sp[i], bb + sdo[i]);
            sp[i] += 32;
        }
    };
    const int ph = (quad ^ (l15 & 3) ^ (l15 >> 2)) * 8;
    auto compute = [&](int buf) {
        const short* Ab = sm + buf * 12288;
        const short* Bb = Ab + 4096;
        bf16x8 af[4], bfr[8];
#pragma unroll
        for (int im = 0; im < 4; im++)
            af[im] = *(const bf16x8*)&Ab[(wr0 + im * 16 + l15) * 32 + ph];
#pragma unroll
        for (int in = 0; in < 8; in++)
            bfr[in] = *(const bf16x8*)&Bb[(wc0 + in * 16 + l15) * 32 + ph];
        __builtin_amdgcn_s_setprio(1);
#pragma unroll
        for (int im = 0; im < 4; im++)
#pragma unroll
            for (int in = 0; in < 8; in++)
                acc[im][in] = __builtin_amdgcn_mfma_f32_16x16x32_bf16(af[im], bfr[in], acc[im][in], 0, 0, 0);
        __builtin_amdgcn_s_setprio(0);
    };

    stage(0); stage(1);
    VMW(6);                                    // tile 0 resident
    __builtin_amdgcn_s_barrier();
    asm volatile("" ::: "memory");

    const int nt = K >> 5;                     // 32 K-steps of 32
    int bs = 2, bc = 0;
    for (int t = 0; t < nt - 2; ++t) {
        stage(bs); bs = (bs == 2) ? 0 : bs + 1;
        compute(bc); bc = (bc == 2) ? 0 : bc + 1;
        SYNC(6);                               // tile t+1 resident
    }
    compute(bc); bc = (bc == 2) ? 0 : bc + 1;  // tile nt-2
    SYNC(0);
    compute(bc);                               // tile nt-1
}

// QKV projection.  grid (32, 4, 3).
// z=0: Q = x*Wq (pre-scaled by 0.125*log2e), stored [bh][s][a]
// z=1: K = x*Wk, stored [bh][s][a]
// z=2: V^T computed directly as Wv^T * x^T, stored [b][h*64+a][s]
__global__ __launch_bounds__(256, 2) void gemm_qkv(
    const short* __restrict__ xb,
    const short* __restrict__ wqT, const short* __restrict__ wkT, const short* __restrict__ wvT,
    const float* __restrict__ bq, const float* __restrict__ bk, const float* __restrict__ bv,
    unsigned short* __restrict__ qb, unsigned short* __restrict__ kb, unsigned short* __restrict__ vTb) {
    __shared__ short sm[36864];            // 3 x (A 4096 + B 8192) = 72KB
    const int z = blockIdx.z;
    const short* Amat = (z == 2) ? wvT : xb;
    const short* Bmat = (z == 0) ? wqT : (z == 1) ? wkT : xb;
    const float* bias = (z == 0) ? bq : (z == 1) ? bk : bv;
    const float scl = (z == 0) ? 0.125f * LOG2E : 1.f;
    int bm0, bn0;
    if (z == 2) {                          // C = VT: 1024 rows(a) x 4096 cols(s)
        int flat = blockIdx.y * 32 + blockIdx.x;    // 0..127
        bm0 = (flat & 7) * 128;
        bn0 = (flat >> 3) * 256;
    } else {                               // C: 4096 rows(s) x 1024 cols(ha)
        bm0 = blockIdx.x * 128;
        bn0 = blockIdx.y * 256;
    }
    f32x4 acc[4][8];
    gemm_core(Amat, Bmat, 1024, bm0, bn0, sm, acc);
    const int lane = threadIdx.x & 63, w = threadIdx.x >> 6;
    const int wr0 = (w >> 1) * 64, wc0 = (w & 1) * 128, l15 = lane & 15, quad = lane >> 4;
    if (z == 2) {
        for (int im = 0; im < 4; im++)
            for (int in = 0; in < 8; in++)
                for (int r = 0; r < 4; r++) {
                    int rowa = bm0 + wr0 + im * 16 + quad * 4 + r;   // h*64+a
                    int colg = bn0 + wc0 + in * 16 + l15;            // b*2048+s
                    unsigned short ov = f2bf(acc[im][in][r] + bias[rowa]);
                    int b = colg >> 11, s = colg & 2047;
                    vTb[(size_t)b * 2097152 + (size_t)rowa * 2048 + s] = ov;
                }
    } else {
        for (int im = 0; im < 4; im++)
            for (int in = 0; in < 8; in++)
                for (int r = 0; r < 4; r++) {
                    int rowg = bm0 + wr0 + im * 16 + quad * 4 + r;   // b*2048+s
                    int colg = bn0 + wc0 + in * 16 + l15;            // h*64+a
                    unsigned short ov = f2bf((acc[im][in][r] + bias[colg]) * scl);
                    int b = rowg >> 11, s = rowg & 2047;
                    int h = colg >> 6, a = colg & 63;
                    int bh = b * 16 + h;
                    if (z == 0) qb[((size_t)bh * 2048 + s) * 64 + a] = ov;
                    else        kb[((size_t)bh * 2048 + s) * 64 + a] = ov;
                }
    }
}

__global__ __launch_bounds__(256, 2) void gemm_out(
    const short* __restrict__ att, const short* __restrict__ woT,
    const float* __restrict__ bo, float* __restrict__ out) {
    __shared__ short sm[36864];
    const int bm0 = blockIdx.x * 128, bn0 = blockIdx.y * 256;
    f32x4 acc[4][8];
    gemm_core(att, woT, 1024, bm0, bn0, sm, acc);
    const int lane = threadIdx.x & 63, w = threadIdx.x >> 6;
    const int wr0 = (w >> 1) * 64, wc0 = (w & 1) * 128, l15 = lane & 15, quad = lane >> 4;
    for (int im = 0; im < 4; im++)
        for (int in = 0; in < 8; in++)
            for (int r = 0; r < 4; r++) {
                int rowg = bm0 + wr0 + im * 16 + quad * 4 + r;
                int colg = bn0 + wc0 + in * 16 + l15;
                out[(size_t)rowg * 1024 + colg] = acc[im][in][r] + bo[colg];
            }
}

// ---------------------------------------------------------------- flash attn
// (reverted to the Round-5 version: best measured 46.4us, FETCH 12.4MB)
// 1D grid 512 (XCD-swizzled); 256 thr = 4 waves, each owns 32 q-cols.
// BKV=64, HD=64. S^T = K*Q^T, O^T = V^T*P^T; softmax w/o max-subtraction.
// T15 pipeline (PV deferred one tile); 4-buffer K/V LDS, depth-3 prefetch,
// counted vmcnt + raw barrier; P in registers (cvt_pk + permlane).
__global__ __launch_bounds__(256, 2) void flash_attn(
    const unsigned short* __restrict__ qb, const unsigned short* __restrict__ kb,
    const unsigned short* __restrict__ vTb, unsigned short* __restrict__ att) {
    __shared__ short Ks[4][4096];
    __shared__ short Vs[4][4096];
    const int tid = threadIdx.x, lane = tid & 63, w = tid >> 6;
    const int l15 = lane & 15, quad = lane >> 4;
    const int lid = ((blockIdx.x & 7) << 6) | (blockIdx.x >> 3);   // XCD swizzle
    const int q0 = (lid & 15) * 128;
    const int bh = lid >> 4;
    const size_t qkbase = (size_t)bh * 2048 * 64;
    const size_t vbase = (size_t)bh * 64 * 2048;
    const int sr = lane >> 3;                  // staging row (8 rows / 1KB call)
    const int slog = (lane & 7) ^ sr;          // swizzled chunk to fetch
    const int l7 = l15 & 7;

    // per-wave staging: waves 0-1 own K rows (32 each), waves 2-3 own V rows
    const unsigned short* sgp;
    int sgstep, sgr;
    short* sgb;
    if (w < 2) {
        sgp = kb + qkbase + (size_t)(w * 32 + sr) * 64 + slog * 8;
        sgstep = 4096; sgr = 512;
        sgb = &Ks[0][0] + w * 2048;
    } else {
        sgp = vTb + vbase + (size_t)((w - 2) * 32 + sr) * 2048 + slog * 8;
        sgstep = 64; sgr = 16384;
        sgb = &Vs[0][0] + (w - 2) * 2048;
    }
    auto stage_tile = [&](int buf) {           // 4 gl2lds per wave per tile
        short* sd = sgb + buf * 4096;
        gl2lds16(sgp, sd);
        gl2lds16(sgp + sgr, sd + 512);
        gl2lds16(sgp + 2 * sgr, sd + 1024);
        gl2lds16(sgp + 3 * sgr, sd + 1536);
        sgp += sgstep;
    };

    const int wq0 = w * 32;
    const int c0 = (quad ^ l7) * 8, c1 = c0 ^ 32;   // swizzled d-chunk offsets (LDS)
    const int fb = l15 * 64;                        // fragment row base

    // Q fragments direct from global (B-operand layout: row=l15, k=quad*8+j)
    const unsigned short* qrow = qb + qkbase + (size_t)(q0 + wq0 + l15) * 64 + quad * 8;
    bf16x8 aq00 = *(const bf16x8*)qrow;
    bf16x8 aq01 = *(const bf16x8*)(qrow + 32);
    bf16x8 aq10 = *(const bf16x8*)(qrow + 1024);
    bf16x8 aq11 = *(const bf16x8*)(qrow + 1024 + 32);

    stage_tile(0); stage_tile(1); stage_tile(2);
    VMW(4);                                     // tiles 0,1 resident
    __builtin_amdgcn_s_barrier();
    asm volatile("" ::: "memory");

    f32x4 o0[4], o1[4];
#pragma unroll
    for (int dt = 0; dt < 4; dt++) { o0[dt] = (f32x4)0.f; o1[dt] = (f32x4)0.f; }
    f32x4 ls0 = (f32x4)0.f, ls1 = (f32x4)0.f;

    auto load_kf = [&](bf16x8* kf, int buf) {
        const short* Kb = &Ks[0][0] + buf * 4096;
#pragma unroll
        for (int t = 0; t < 4; t++) {
            kf[2 * t]     = *(const bf16x8*)(Kb + fb + c0 + t * 1024);
            kf[2 * t + 1] = *(const bf16x8*)(Kb + fb + c1 + t * 1024);
        }
    };
    bf16x8 vf[8];                                    // single V bank
    auto load_vf = [&](int buf) {
        const short* Vb = &Vs[0][0] + buf * 4096;
#pragma unroll
        for (int t = 0; t < 4; t++) {
            vf[2 * t]     = *(const bf16x8*)(Vb + fb + c0 + t * 1024);
            vf[2 * t + 1] = *(const bf16x8*)(Vb + fb + c1 + t * 1024);
        }
    };

    auto qk = [&](const bf16x8* kf, f32x4* sc0, f32x4* sc1) {
        __builtin_amdgcn_s_setprio(1);
#pragma unroll
        for (int t = 0; t < 4; t++) {
            sc0[t] = __builtin_amdgcn_mfma_f32_16x16x32_bf16(kf[2 * t], aq00, (f32x4)0.f, 0, 0, 0);
            sc1[t] = __builtin_amdgcn_mfma_f32_16x16x32_bf16(kf[2 * t], aq10, (f32x4)0.f, 0, 0, 0);
        }
#pragma unroll
        for (int t = 0; t < 4; t++) {
            sc0[t] = __builtin_amdgcn_mfma_f32_16x16x32_bf16(kf[2 * t + 1], aq01, sc0[t], 0, 0, 0);
            sc1[t] = __builtin_amdgcn_mfma_f32_16x16x32_bf16(kf[2 * t + 1], aq11, sc1[t], 0, 0, 0);
        }
        __builtin_amdgcn_s_setprio(0);
    };

    // exp2 + row-sum + in-register P transpose (C-frag -> PV B-frag)
    auto smax = [&](f32x4 (&sc)[4], f32x4& lsr, bf16x8* bp) {
#pragma unroll
        for (int t = 0; t < 4; t++) {
#pragma unroll
            for (int r = 0; r < 4; r++) sc[t][r] = __ocml_native_exp2_f32(sc[t][r]);
            lsr += sc[t];
        }
#pragma unroll
        for (int t2 = 0; t2 < 2; t2++) {
            unsigned pa = pk_bf16(sc[2 * t2][0], sc[2 * t2][1]);
            unsigned pb = pk_bf16(sc[2 * t2][2], sc[2 * t2][3]);
            unsigned pc = pk_bf16(sc[2 * t2 + 1][0], sc[2 * t2 + 1][1]);
            unsigned pd = pk_bf16(sc[2 * t2 + 1][2], sc[2 * t2 + 1][3]);
            asm("v_permlane32_swap_b32 %0, %1" : "+v"(pa), "+v"(pc));
            asm("v_permlane32_swap_b32 %0, %1" : "+v"(pb), "+v"(pd));
            asm("v_permlane16_swap_b32 %0, %1" : "+v"(pa), "+v"(pc));
            asm("v_permlane16_swap_b32 %0, %1" : "+v"(pb), "+v"(pd));
            union { unsigned u[4]; bf16x8 v; } cvt;
            cvt.u[0] = pa; cvt.u[1] = pb; cvt.u[2] = pc; cvt.u[3] = pd;
            bp[t2] = cvt.v;
        }
    };

    auto pv = [&](const bf16x8* bp) {       // PV from bp bank + current vf
        __builtin_amdgcn_s_setprio(1);
#pragma unroll
        for (int t2 = 0; t2 < 2; t2++)
#pragma unroll
            for (int dt = 0; dt < 4; dt++) {
                o0[dt] = __builtin_amdgcn_mfma_f32_16x16x32_bf16(vf[2 * dt + t2], bp[t2], o0[dt], 0, 0, 0);
                o1[dt] = __builtin_amdgcn_mfma_f32_16x16x32_bf16(vf[2 * dt + t2], bp[2 + t2], o1[dt], 0, 0, 0);
            }
        __builtin_amdgcn_s_setprio(0);
    };

    bf16x8 kfA[8], kfB[8];
    bf16x8 bpA[4], bpB[4];

    load_kf(kfA, 0);
    asm volatile("s_waitcnt lgkmcnt(0)" ::: "memory");
    __builtin_amdgcn_sched_barrier(0);

    // step body: kfC = tile t frags, kfN <- tile t+1, bpC <- bp(t),
    // bpP = bp(t-1) consumed by PV(t-1) together with vf (holding t-1).
    auto step = [&](int t, const bf16x8* kfC, bf16x8* kfN, bf16x8* bpC,
                    const bf16x8* bpP, bool dokf, bool dopv, bool dostage) {
        if (dokf) load_kf(kfN, (t + 1) & 3);
        __builtin_amdgcn_sched_barrier(0);   // pin kf reads early (hide latency)
        f32x4 sc0[4], sc1[4];
        qk(kfC, sc0, sc1);
        smax(sc0, ls0, bpC);
        smax(sc1, ls1, bpC + 2);
        if (dopv) pv(bpP);
        load_vf(t & 3);                      // after PV consumed vf(t-1)
        if (dostage) stage_tile((t + 3) & 3);
    };

    step(0, kfA, kfB, bpA, bpB, true, false, true); SYNC(4);
    for (int t = 1; t < 29; t += 2) {
        step(t,     kfB, kfA, bpB, bpA, true, true, true); SYNC(4);
        step(t + 1, kfA, kfB, bpA, bpB, true, true, true); SYNC(4);
    }
    step(29, kfB, kfA, bpB, bpA, true, true, false); SYNC(0);
    step(30, kfA, kfB, bpA, bpB, true, true, false); SYNC(0);
    step(31, kfB, kfA, bpB, bpA, false, true, false);
    asm volatile("s_waitcnt lgkmcnt(0)" ::: "memory");   // vf(31) landed
    pv(bpB);                                             // final PV(31)

    const int b = bh >> 4, h = bh & 15;
    float l0 = (ls0[0] + ls0[1]) + (ls0[2] + ls0[3]);
    l0 += __shfl_xor(l0, 16);
    l0 += __shfl_xor(l0, 32);
    float inv0 = 1.f / l0;
    float l1 = (ls1[0] + ls1[1]) + (ls1[2] + ls1[3]);
    l1 += __shfl_xor(l1, 16);
    l1 += __shfl_xor(l1, 32);
    float inv1 = 1.f / l1;
    int s = q0 + wq0 + l15;
#pragma unroll
    for (int dt = 0; dt < 4; dt++) {
        int col = h * 64 + dt * 16 + quad * 4;
        uint2 pk;
        pk.x = pk_bf16(o0[dt][0] * inv0, o0[dt][1] * inv0);
        pk.y = pk_bf16(o0[dt][2] * inv0, o0[dt][3] * inv0);
        *(uint2*)&att[((size_t)b * 2048 + s) * 1024 + col] = pk;
        pk.x = pk_bf16(o1[dt][0] * inv1, o1[dt][1] * inv1);
        pk.y = pk_bf16(o1[dt][2] * inv1, o1[dt][3] * inv1);
        *(uint2*)&att[((size_t)b * 2048 + s + 16) * 1024 + col] = pk;
    }
}

extern "C" void kernel_launch(void* const* d_in, const int* in_sizes, int n_in,
                              void* d_out, int out_size, void* d_ws, size_t ws_size,
                              hipStream_t stream) {
    const float* x  = (const float*)d_in[0];
    const float* Wq = (const float*)d_in[1];
    const float* bq = (const float*)d_in[2];
    const float* Wk = (const float*)d_in[3];
    const float* bk = (const float*)d_in[4];
    const float* Wv = (const float*)d_in[5];
    const float* bv = (const float*)d_in[6];
    const float* Wo = (const float*)d_in[7];
    const float* bo = (const float*)d_in[8];
    float* out = (float*)d_out;

    short* ws  = (short*)d_ws;
    short* xb  = ws;                          // 4M shorts
    short* wqT = ws + 4 * 1024 * 1024;        // 1M each
    short* wkT = wqT + 1024 * 1024;
    short* wvT = wkT + 1024 * 1024;
    short* woT = wvT + 1024 * 1024;
    short* qb  = woT + 1024 * 1024;           // 4M each
    short* kb  = qb + 4 * 1024 * 1024;
    short* vTb = kb + 4 * 1024 * 1024;
    short* att = vTb + 4 * 1024 * 1024;       // total 24M shorts = 48MB

    cvt_bf16<<<4096, 256, 0, stream>>>(x, (unsigned int*)xb, 1024 * 1024);
    transpose4_bf16<<<dim3(32, 32, 4), 256, 0, stream>>>(
        Wq, Wk, Wv, Wo,
        (unsigned short*)wqT, (unsigned short*)wkT,
        (unsigned short*)wvT, (unsigned short*)woT);
    gemm_qkv<<<dim3(32, 4, 3), 256, 0, stream>>>(xb, wqT, wkT, wvT, bq, bk, bv,
                                                 (unsigned short*)qb, (unsigned short*)kb,
                                                 (unsigned short*)vTb);
    flash_attn<<<512, 256, 0, stream>>>((const unsigned short*)qb,
                                        (const unsigned short*)kb,
                                        (const unsigned short*)vTb,
                                        (unsigned short*)att);
    gemm_out<<<dim3(32, 4), 256, 0, stream>>>(att, woT, bo, out);
}

// Round 8
// 177.328 us; speedup vs baseline: 1.1467x; 1.0767x over previous
//
#include <hip/hip_runtime.h>
#include <hip/hip_bf16.h>

typedef __attribute__((ext_vector_type(8))) short bf16x8;
typedef __attribute__((ext_vector_type(4))) float f32x4;

#define LOG2E 1.44269504088896f

extern "C" __device__ float __ocml_native_exp2_f32(float);   // raw v_exp_f32

__device__ __forceinline__ unsigned short f2bf(float f) {
    union { float f; unsigned int u; } v; v.f = f;
    unsigned int r = v.u + 0x7FFF + ((v.u >> 16) & 1);   // RNE to bf16
    return (unsigned short)(r >> 16);
}

// gfx950 packed f32x2 -> bf16x2 (RNE), one VALU inst
__device__ __forceinline__ unsigned int pk_bf16(float lo, float hi) {
    unsigned int r;
    asm("v_cvt_pk_bf16_f32 %0, %1, %2" : "=v"(r) : "v"(lo), "v"(hi));
    return r;
}

typedef __attribute__((address_space(3))) unsigned int lds_uint;
typedef __attribute__((address_space(1))) const unsigned int glob_uint;
__device__ __forceinline__ void gl2lds16(const void* g, void* l) {
    __builtin_amdgcn_global_load_lds((glob_uint*)g, (lds_uint*)l, 16, 0, 0);
}

#define VMW(n) asm volatile("s_waitcnt vmcnt(" #n ")" ::: "memory")

// vmcnt(N) + lgkmcnt(0) + barrier (pipeline sync)
#define SYNC(vm)                                                             \
    asm volatile("s_waitcnt vmcnt(" #vm ")\n\ts_waitcnt lgkmcnt(0)" ::: "memory"); \
    __builtin_amdgcn_s_barrier();                                            \
    asm volatile("" ::: "memory")

// ---------------------------------------------------------------- prep
// Fused x fp32->bf16 cast (blocks 0..4095) + 4x 1024x1024 fp32->bf16
// transposes (blocks 4096..8191). One launch instead of two: the pipeline
// carries a fixed ~10us/launch dispatch cost (total - flash is a constant
// 131.6us across R5-R7 while per-kernel work sums to ~66us).
__global__ __launch_bounds__(256) void prep(
    const float* __restrict__ x,
    const float* __restrict__ w0, const float* __restrict__ w1,
    const float* __restrict__ w2, const float* __restrict__ w3,
    unsigned int* __restrict__ xb,
    unsigned short* __restrict__ o0, unsigned short* __restrict__ o1,
    unsigned short* __restrict__ o2, unsigned short* __restrict__ o3) {
    __shared__ float t[32][33];
    const int bid = blockIdx.x;
    if (bid < 4096) {                       // cvt: 4096 blocks x 256 thr x 4 f
        int i = bid * 256 + threadIdx.x;
        float4 v = ((const float4*)x)[i];
        uint2 o;
        o.x = pk_bf16(v.x, v.y);
        o.y = pk_bf16(v.z, v.w);
        ((uint2*)xb)[i] = o;
    } else {                                // transpose: 4 x 1024 blocks
        int tt = bid - 4096;
        int z = tt >> 10;
        tt &= 1023;
        const float* in = (z == 0) ? w0 : (z == 1) ? w1 : (z == 2) ? w2 : w3;
        unsigned short* out = (z == 0) ? o0 : (z == 1) ? o1 : (z == 2) ? o2 : o3;
        int tx = threadIdx.x & 31, ty = threadIdx.x >> 5;
        int r0 = (tt >> 5) * 32, c0 = (tt & 31) * 32;
        for (int i = 0; i < 32; i += 8)
            t[ty + i][tx] = in[(size_t)(r0 + ty + i) * 1024 + c0 + tx];
        __syncthreads();
        for (int i = 0; i < 32; i += 8)
            out[(size_t)(c0 + ty + i) * 1024 + r0 + tx] = f2bf(t[tx][ty + i]);
    }
}

// ---------------------------------------------------------------- GEMM core
// C[128x128] = A[128xK] * BT[128xK]^T ; 256 thr, 4 waves each 64x64.
// 3-buffer LDS pipeline + register double-buffered fragments (R5 form,
// best measured). LDS rows are 32 shorts (4 chunks of 16B); chunk position
// XOR-swizzled by (row&3)^(row>>2) on both store and read sides.
__device__ __forceinline__ void gemm_core(const short* __restrict__ A,
                                          const short* __restrict__ BT,
                                          int K, int bm0, int bn0,
                                          short* sm, f32x4 acc[4][4]) {
    const int tid = threadIdx.x;
    const int lane = tid & 63;
    const int w = tid >> 6;
    const int wr0 = (w >> 1) * 64;
    const int wc0 = (w & 1) * 64;
    const int l15 = lane & 15, quad = lane >> 4;
    const int sr = lane >> 2;                              // staging row in 16-row chunk
    const int slog = (lane & 3) ^ (sr & 3) ^ (sr >> 2);    // swizzled k-chunk to fetch

#pragma unroll
    for (int i = 0; i < 4; i++)
#pragma unroll
        for (int j = 0; j < 4; j++) acc[i][j] = (f32x4)0.f;

    const short* sp[4];
    int sdo[4];
#pragma unroll
    for (int i = 0; i < 4; i++) {
        int c = w * 4 + i;
        sp[i] = (c < 8) ? A + (size_t)(bm0 + c * 16 + sr) * K + slog * 8
                        : BT + (size_t)(bn0 + (c - 8) * 16 + sr) * K + slog * 8;
        sdo[i] = c * 512;
    }
    auto stage = [&](int buf) {
        short* bb = sm + buf * 8192;
#pragma unroll
        for (int i = 0; i < 4; i++) {
            gl2lds16(sp[i], bb + sdo[i]);
            sp[i] += 32;
        }
    };
    const int ph = (quad ^ (l15 & 3) ^ (l15 >> 2)) * 8;
    auto loadf = [&](bf16x8* af, bf16x8* bfr, int buf) {
        const short* Ab = sm + buf * 8192;
        const short* Bb = Ab + 4096;
#pragma unroll
        for (int im = 0; im < 4; im++)
            af[im] = *(const bf16x8*)&Ab[(wr0 + im * 16 + l15) * 32 + ph];
#pragma unroll
        for (int in = 0; in < 4; in++)
            bfr[in] = *(const bf16x8*)&Bb[(wc0 + in * 16 + l15) * 32 + ph];
        __builtin_amdgcn_sched_barrier(0);   // pin reads here (issue-early)
    };
    auto computef = [&](const bf16x8* af, const bf16x8* bfr) {
        __builtin_amdgcn_s_setprio(1);
#pragma unroll
        for (int im = 0; im < 4; im++)
#pragma unroll
            for (int in = 0; in < 4; in++)
                acc[im][in] = __builtin_amdgcn_mfma_f32_16x16x32_bf16(af[im], bfr[in], acc[im][in], 0, 0, 0);
        __builtin_amdgcn_s_setprio(0);
    };

    stage(0); stage(1);
    VMW(4);                                            // tile 0 resident
    __builtin_amdgcn_s_barrier();
    asm volatile("" ::: "memory");

    bf16x8 aA[4], bA[4], aB[4], bB[4];
    loadf(aA, bA, 0);

    const int nt = K >> 5;                 // 32 K-steps of 32
    int bs = 2, rb = 1;
    for (int t = 0; t < nt - 2; t += 2) {
        stage(bs); bs = (bs == 2) ? 0 : bs + 1;
        SYNC(4);                                   // tile t+1 resident
        loadf(aB, bB, rb); rb = (rb == 2) ? 0 : rb + 1;
        computef(aA, bA);                          // tile t
        stage(bs); bs = (bs == 2) ? 0 : bs + 1;
        SYNC(4);                                   // tile t+2 resident
        loadf(aA, bA, rb); rb = (rb == 2) ? 0 : rb + 1;
        computef(aB, bB);                          // tile t+1
    }
    SYNC(0);                                       // tile nt-1 resident
    loadf(aB, bB, rb);
    computef(aA, bA);                              // tile nt-2
    computef(aB, bB);                              // tile nt-1
}

// QKV projection.  grid (32, 8, 3).
// z=0: Q = x*Wq (pre-scaled by 0.125*log2e), stored [bh][s][a]
// z=1: K = x*Wk, stored [bh][s][a]
// z=2: V^T computed directly as Wv^T * x^T, stored [b][h*64+a][s]
__global__ __launch_bounds__(256, 3) void gemm_qkv(
    const short* __restrict__ xb,
    const short* __restrict__ wqT, const short* __restrict__ wkT, const short* __restrict__ wvT,
    const float* __restrict__ bq, const float* __restrict__ bk, const float* __restrict__ bv,
    unsigned short* __restrict__ qb, unsigned short* __restrict__ kb, unsigned short* __restrict__ vTb) {
    __shared__ short sm[24576];            // 3 x (A 4096 + B 4096) = 48KB
    const int z = blockIdx.z;
    const short* Amat = (z == 2) ? wvT : xb;
    const short* Bmat = (z == 0) ? wqT : (z == 1) ? wkT : xb;
    const float* bias = (z == 0) ? bq : (z == 1) ? bk : bv;
    const float scl = (z == 0) ? 0.125f * LOG2E : 1.f;
    const int bm0 = (z == 2) ? blockIdx.y * 128 : blockIdx.x * 128;
    const int bn0 = (z == 2) ? blockIdx.x * 128 : blockIdx.y * 128;
    f32x4 acc[4][4];
    gemm_core(Amat, Bmat, 1024, bm0, bn0, sm, acc);
    const int lane = threadIdx.x & 63, w = threadIdx.x >> 6;
    const int wr0 = (w >> 1) * 64, wc0 = (w & 1) * 64, l15 = lane & 15, quad = lane >> 4;
    if (z == 2) {
        for (int im = 0; im < 4; im++)
            for (int in = 0; in < 4; in++)
                for (int r = 0; r < 4; r++) {
                    int rowa = bm0 + wr0 + im * 16 + quad * 4 + r;   // h*64+a
                    int colg = bn0 + wc0 + in * 16 + l15;            // b*2048+s
                    unsigned short ov = f2bf(acc[im][in][r] + bias[rowa]);
                    int b = colg >> 11, s = colg & 2047;
                    vTb[(size_t)b * 2097152 + (size_t)rowa * 2048 + s] = ov;
                }
    } else {
        for (int im = 0; im < 4; im++)
            for (int in = 0; in < 4; in++)
                for (int r = 0; r < 4; r++) {
                    int rowg = bm0 + wr0 + im * 16 + quad * 4 + r;   // b*2048+s
                    int colg = bn0 + wc0 + in * 16 + l15;            // h*64+a
                    unsigned short ov = f2bf((acc[im][in][r] + bias[colg]) * scl);
                    int b = rowg >> 11, s = rowg & 2047;
                    int h = colg >> 6, a = colg & 63;
                    int bh = b * 16 + h;
                    if (z == 0) qb[((size_t)bh * 2048 + s) * 64 + a] = ov;
                    else        kb[((size_t)bh * 2048 + s) * 64 + a] = ov;
                }
    }
}

__global__ __launch_bounds__(256, 3) void gemm_out(
    const short* __restrict__ att, const short* __restrict__ woT,
    const float* __restrict__ bo, float* __restrict__ out) {
    __shared__ short sm[24576];
    const int bm0 = blockIdx.x * 128, bn0 = blockIdx.y * 128;
    f32x4 acc[4][4];
    gemm_core(att, woT, 1024, bm0, bn0, sm, acc);
    const int lane = threadIdx.x & 63, w = threadIdx.x >> 6;
    const int wr0 = (w >> 1) * 64, wc0 = (w & 1) * 64, l15 = lane & 15, quad = lane >> 4;
    for (int im = 0; im < 4; im++)
        for (int in = 0; in < 4; in++)
            for (int r = 0; r < 4; r++) {
                int rowg = bm0 + wr0 + im * 16 + quad * 4 + r;
                int colg = bn0 + wc0 + in * 16 + l15;
                out[(size_t)rowg * 1024 + colg] = acc[im][in][r] + bo[colg];
            }
}

// ---------------------------------------------------------------- flash attn
// (Round-5 version: best measured 46.0-46.4us, FETCH 12.4MB)
// 1D grid 512 (XCD-swizzled); 256 thr = 4 waves, each owns 32 q-cols.
// BKV=64, HD=64. S^T = K*Q^T, O^T = V^T*P^T; softmax w/o max-subtraction.
// T15 pipeline (PV deferred one tile); 4-buffer K/V LDS, depth-3 prefetch,
// counted vmcnt + raw barrier; P in registers (cvt_pk + permlane).
__global__ __launch_bounds__(256, 2) void flash_attn(
    const unsigned short* __restrict__ qb, const unsigned short* __restrict__ kb,
    const unsigned short* __restrict__ vTb, unsigned short* __restrict__ att) {
    __shared__ short Ks[4][4096];
    __shared__ short Vs[4][4096];
    const int tid = threadIdx.x, lane = tid & 63, w = tid >> 6;
    const int l15 = lane & 15, quad = lane >> 4;
    const int lid = ((blockIdx.x & 7) << 6) | (blockIdx.x >> 3);   // XCD swizzle
    const int q0 = (lid & 15) * 128;
    const int bh = lid >> 4;
    const size_t qkbase = (size_t)bh * 2048 * 64;
    const size_t vbase = (size_t)bh * 64 * 2048;
    const int sr = lane >> 3;                  // staging row (8 rows / 1KB call)
    const int slog = (lane & 7) ^ sr;          // swizzled chunk to fetch
    const int l7 = l15 & 7;

    // per-wave staging: waves 0-1 own K rows (32 each), waves 2-3 own V rows
    const unsigned short* sgp;
    int sgstep, sgr;
    short* sgb;
    if (w < 2) {
        sgp = kb + qkbase + (size_t)(w * 32 + sr) * 64 + slog * 8;
        sgstep = 4096; sgr = 512;
        sgb = &Ks[0][0] + w * 2048;
    } else {
        sgp = vTb + vbase + (size_t)((w - 2) * 32 + sr) * 2048 + slog * 8;
        sgstep = 64; sgr = 16384;
        sgb = &Vs[0][0] + (w - 2) * 2048;
    }
    auto stage_tile = [&](int buf) {           // 4 gl2lds per wave per tile
        short* sd = sgb + buf * 4096;
        gl2lds16(sgp, sd);
        gl2lds16(sgp + sgr, sd + 512);
        gl2lds16(sgp + 2 * sgr, sd + 1024);
        gl2lds16(sgp + 3 * sgr, sd + 1536);
        sgp += sgstep;
    };

    const int wq0 = w * 32;
    const int c0 = (quad ^ l7) * 8, c1 = c0 ^ 32;   // swizzled d-chunk offsets (LDS)
    const int fb = l15 * 64;                        // fragment row base

    // Q fragments direct from global (B-operand layout: row=l15, k=quad*8+j)
    const unsigned short* qrow = qb + qkbase + (size_t)(q0 + wq0 + l15) * 64 + quad * 8;
    bf16x8 aq00 = *(const bf16x8*)qrow;
    bf16x8 aq01 = *(const bf16x8*)(qrow + 32);
    bf16x8 aq10 = *(const bf16x8*)(qrow + 1024);
    bf16x8 aq11 = *(const bf16x8*)(qrow + 1024 + 32);

    stage_tile(0); stage_tile(1); stage_tile(2);
    VMW(4);                                     // tiles 0,1 resident
    __builtin_amdgcn_s_barrier();
    asm volatile("" ::: "memory");

    f32x4 o0[4], o1[4];
#pragma unroll
    for (int dt = 0; dt < 4; dt++) { o0[dt] = (f32x4)0.f; o1[dt] = (f32x4)0.f; }
    f32x4 ls0 = (f32x4)0.f, ls1 = (f32x4)0.f;

    auto load_kf = [&](bf16x8* kf, int buf) {
        const short* Kb = &Ks[0][0] + buf * 4096;
#pragma unroll
        for (int t = 0; t < 4; t++) {
            kf[2 * t]     = *(const bf16x8*)(Kb + fb + c0 + t * 1024);
            kf[2 * t + 1] = *(const bf16x8*)(Kb + fb + c1 + t * 1024);
        }
    };
    bf16x8 vf[8];                                    // single V bank
    auto load_vf = [&](int buf) {
        const short* Vb = &Vs[0][0] + buf * 4096;
#pragma unroll
        for (int t = 0; t < 4; t++) {
            vf[2 * t]     = *(const bf16x8*)(Vb + fb + c0 + t * 1024);
            vf[2 * t + 1] = *(const bf16x8*)(Vb + fb + c1 + t * 1024);
        }
    };

    auto qk = [&](const bf16x8* kf, f32x4* sc0, f32x4* sc1) {
        __builtin_amdgcn_s_setprio(1);
#pragma unroll
        for (int t = 0; t < 4; t++) {
            sc0[t] = __builtin_amdgcn_mfma_f32_16x16x32_bf16(kf[2 * t], aq00, (f32x4)0.f, 0, 0, 0);
            sc1[t] = __builtin_amdgcn_mfma_f32_16x16x32_bf16(kf[2 * t], aq10, (f32x4)0.f, 0, 0, 0);
        }
#pragma unroll
        for (int t = 0; t < 4; t++) {
            sc0[t] = __builtin_amdgcn_mfma_f32_16x16x32_bf16(kf[2 * t + 1], aq01, sc0[t], 0, 0, 0);
            sc1[t] = __builtin_amdgcn_mfma_f32_16x16x32_bf16(kf[2 * t + 1], aq11, sc1[t], 0, 0, 0);
        }
        __builtin_amdgcn_s_setprio(0);
    };

    // exp2 + row-sum + in-register P transpose (C-frag -> PV B-frag)
    auto smax = [&](f32x4 (&sc)[4], f32x4& lsr, bf16x8* bp) {
#pragma unroll
        for (int t = 0; t < 4; t++) {
#pragma unroll
            for (int r = 0; r < 4; r++) sc[t][r] = __ocml_native_exp2_f32(sc[t][r]);
            lsr += sc[t];
        }
#pragma unroll
        for (int t2 = 0; t2 < 2; t2++) {
            unsigned pa = pk_bf16(sc[2 * t2][0], sc[2 * t2][1]);
            unsigned pb = pk_bf16(sc[2 * t2][2], sc[2 * t2][3]);
            unsigned pc = pk_bf16(sc[2 * t2 + 1][0], sc[2 * t2 + 1][1]);
            unsigned pd = pk_bf16(sc[2 * t2 + 1][2], sc[2 * t2 + 1][3]);
            asm("v_permlane32_swap_b32 %0, %1" : "+v"(pa), "+v"(pc));
            asm("v_permlane32_swap_b32 %0, %1" : "+v"(pb), "+v"(pd));
            asm("v_permlane16_swap_b32 %0, %1" : "+v"(pa), "+v"(pc));
            asm("v_permlane16_swap_b32 %0, %1" : "+v"(pb), "+v"(pd));
            union { unsigned u[4]; bf16x8 v; } cvt;
            cvt.u[0] = pa; cvt.u[1] = pb; cvt.u[2] = pc; cvt.u[3] = pd;
            bp[t2] = cvt.v;
        }
    };

    auto pv = [&](const bf16x8* bp) {       // PV from bp bank + current vf
        __builtin_amdgcn_s_setprio(1);
#pragma unroll
        for (int t2 = 0; t2 < 2; t2++)
#pragma unroll
            for (int dt = 0; dt < 4; dt++) {
                o0[dt] = __builtin_amdgcn_mfma_f32_16x16x32_bf16(vf[2 * dt + t2], bp[t2], o0[dt], 0, 0, 0);
                o1[dt] = __builtin_amdgcn_mfma_f32_16x16x32_bf16(vf[2 * dt + t2], bp[2 + t2], o1[dt], 0, 0, 0);
            }
        __builtin_amdgcn_s_setprio(0);
    };

    bf16x8 kfA[8], kfB[8];
    bf16x8 bpA[4], bpB[4];

    load_kf(kfA, 0);
    asm volatile("s_waitcnt lgkmcnt(0)" ::: "memory");
    __builtin_amdgcn_sched_barrier(0);

    // step body: kfC = tile t frags, kfN <- tile t+1, bpC <- bp(t),
    // bpP = bp(t-1) consumed by PV(t-1) together with vf (holding t-1).
    auto step = [&](int t, const bf16x8* kfC, bf16x8* kfN, bf16x8* bpC,
                    const bf16x8* bpP, bool dokf, bool dopv, bool dostage) {
        if (dokf) load_kf(kfN, (t + 1) & 3);
        __builtin_amdgcn_sched_barrier(0);   // pin kf reads early (hide latency)
        f32x4 sc0[4], sc1[4];
        qk(kfC, sc0, sc1);
        smax(sc0, ls0, bpC);
        smax(sc1, ls1, bpC + 2);
        if (dopv) pv(bpP);
        load_vf(t & 3);                      // after PV consumed vf(t-1)
        if (dostage) stage_tile((t + 3) & 3);
    };

    step(0, kfA, kfB, bpA, bpB, true, false, true); SYNC(4);
    for (int t = 1; t < 29; t += 2) {
        step(t,     kfB, kfA, bpB, bpA, true, true, true); SYNC(4);
        step(t + 1, kfA, kfB, bpA, bpB, true, true, true); SYNC(4);
    }
    step(29, kfB, kfA, bpB, bpA, true, true, false); SYNC(0);
    step(30, kfA, kfB, bpA, bpB, true, true, false); SYNC(0);
    step(31, kfB, kfA, bpB, bpA, false, true, false);
    asm volatile("s_waitcnt lgkmcnt(0)" ::: "memory");   // vf(31) landed
    pv(bpB);                                             // final PV(31)

    const int b = bh >> 4, h = bh & 15;
    float l0 = (ls0[0] + ls0[1]) + (ls0[2] + ls0[3]);
    l0 += __shfl_xor(l0, 16);
    l0 += __shfl_xor(l0, 32);
    float inv0 = 1.f / l0;
    float l1 = (ls1[0] + ls1[1]) + (ls1[2] + ls1[3]);
    l1 += __shfl_xor(l1, 16);
    l1 += __shfl_xor(l1, 32);
    float inv1 = 1.f / l1;
    int s = q0 + wq0 + l15;
#pragma unroll
    for (int dt = 0; dt < 4; dt++) {
        int col = h * 64 + dt * 16 + quad * 4;
        uint2 pk;
        pk.x = pk_bf16(o0[dt][0] * inv0, o0[dt][1] * inv0);
        pk.y = pk_bf16(o0[dt][2] * inv0, o0[dt][3] * inv0);
        *(uint2*)&att[((size_t)b * 2048 + s) * 1024 + col] = pk;
        pk.x = pk_bf16(o1[dt][0] * inv1, o1[dt][1] * inv1);
        pk.y = pk_bf16(o1[dt][2] * inv1, o1[dt][3] * inv1);
        *(uint2*)&att[((size_t)b * 2048 + s + 16) * 1024 + col] = pk;
    }
}

extern "C" void kernel_launch(void* const* d_in, const int* in_sizes, int n_in,
                              void* d_out, int out_size, void* d_ws, size_t ws_size,
                              hipStream_t stream) {
    const float* x  = (const float*)d_in[0];
    const float* Wq = (const float*)d_in[1];
    const float* bq = (const float*)d_in[2];
    const float* Wk = (const float*)d_in[3];
    const float* bk = (const float*)d_in[4];
    const float* Wv = (const float*)d_in[5];
    const float* bv = (const float*)d_in[6];
    const float* Wo = (const float*)d_in[7];
    const float* bo = (const float*)d_in[8];
    float* out = (float*)d_out;

    short* ws  = (short*)d_ws;
    short* xb  = ws;                          // 4M shorts
    short* wqT = ws + 4 * 1024 * 1024;        // 1M each
    short* wkT = wqT + 1024 * 1024;
    short* wvT = wkT + 1024 * 1024;
    short* woT = wvT + 1024 * 1024;
    short* qb  = woT + 1024 * 1024;           // 4M each
    short* kb  = qb + 4 * 1024 * 1024;
    short* vTb = kb + 4 * 1024 * 1024;
    short* att = vTb + 4 * 1024 * 1024;       // total 24M shorts = 48MB

    prep<<<8192, 256, 0, stream>>>(x, Wq, Wk, Wv, Wo, (unsigned int*)xb,
                                   (unsigned short*)wqT, (unsigned short*)wkT,
                                   (unsigned short*)wvT, (unsigned short*)woT);
    gemm_qkv<<<dim3(32, 8, 3), 256, 0, stream>>>(xb, wqT, wkT, wvT, bq, bk, bv,
                                                 (unsigned short*)qb, (unsigned short*)kb,
                                                 (unsigned short*)vTb);
    flash_attn<<<512, 256, 0, stream>>>((const unsigned short*)qb,
                                        (const unsigned short*)kb,
                                        (const unsigned short*)vTb,
                                        (unsigned short*)att);
    gemm_out<<<dim3(32, 8), 256, 0, stream>>>(att, woT, bo, out);
}

// Round 9
// 176.722 us; speedup vs baseline: 1.1506x; 1.0034x over previous
//
#include <hip/hip_runtime.h>
#include <hip/hip_bf16.h>

typedef __attribute__((ext_vector_type(8))) short bf16x8;
typedef __attribute__((ext_vector_type(4))) float f32x4;

#define LOG2E 1.44269504088896f

extern "C" __device__ float __ocml_native_exp2_f32(float);   // raw v_exp_f32

__device__ __forceinline__ unsigned short f2bf(float f) {
    union { float f; unsigned int u; } v; v.f = f;
    unsigned int r = v.u + 0x7FFF + ((v.u >> 16) & 1);   // RNE to bf16
    return (unsigned short)(r >> 16);
}

// gfx950 packed f32x2 -> bf16x2 (RNE), one VALU inst
__device__ __forceinline__ unsigned int pk_bf16(float lo, float hi) {
    unsigned int r;
    asm("v_cvt_pk_bf16_f32 %0, %1, %2" : "=v"(r) : "v"(lo), "v"(hi));
    return r;
}

typedef __attribute__((address_space(3))) unsigned int lds_uint;
typedef __attribute__((address_space(1))) const unsigned int glob_uint;
__device__ __forceinline__ void gl2lds16(const void* g, void* l) {
    __builtin_amdgcn_global_load_lds((glob_uint*)g, (lds_uint*)l, 16, 0, 0);
}

#define VMW(n) asm volatile("s_waitcnt vmcnt(" #n ")" ::: "memory")

// vmcnt(N) + lgkmcnt(0) + barrier (pipeline sync)
#define SYNC(vm)                                                             \
    asm volatile("s_waitcnt vmcnt(" #vm ")\n\ts_waitcnt lgkmcnt(0)" ::: "memory"); \
    __builtin_amdgcn_s_barrier();                                            \
    asm volatile("" ::: "memory")

// ---------------------------------------------------------------- prep
// Fused x fp32->bf16 cast (blocks 0..4095) + 4x 1024x1024 fp32->bf16
// transposes (blocks 4096..8191).
__global__ __launch_bounds__(256) void prep(
    const float* __restrict__ x,
    const float* __restrict__ w0, const float* __restrict__ w1,
    const float* __restrict__ w2, const float* __restrict__ w3,
    unsigned int* __restrict__ xb,
    unsigned short* __restrict__ o0, unsigned short* __restrict__ o1,
    unsigned short* __restrict__ o2, unsigned short* __restrict__ o3) {
    __shared__ float t[32][33];
    const int bid = blockIdx.x;
    if (bid < 4096) {                       // cvt: 4096 blocks x 256 thr x 4 f
        int i = bid * 256 + threadIdx.x;
        float4 v = ((const float4*)x)[i];
        uint2 o;
        o.x = pk_bf16(v.x, v.y);
        o.y = pk_bf16(v.z, v.w);
        ((uint2*)xb)[i] = o;
    } else {                                // transpose: 4 x 1024 blocks
        int tt = bid - 4096;
        int z = tt >> 10;
        tt &= 1023;
        const float* in = (z == 0) ? w0 : (z == 1) ? w1 : (z == 2) ? w2 : w3;
        unsigned short* out = (z == 0) ? o0 : (z == 1) ? o1 : (z == 2) ? o2 : o3;
        int tx = threadIdx.x & 31, ty = threadIdx.x >> 5;
        int r0 = (tt >> 5) * 32, c0 = (tt & 31) * 32;
        for (int i = 0; i < 32; i += 8)
            t[ty + i][tx] = in[(size_t)(r0 + ty + i) * 1024 + c0 + tx];
        __syncthreads();
        for (int i = 0; i < 32; i += 8)
            out[(size_t)(c0 + ty + i) * 1024 + r0 + tx] = f2bf(t[tx][ty + i]);
    }
}

// ---------------------------------------------------------------- GEMM core
// C[128x128] = A[128xK] * BT[128xK]^T ; 256 thr, 4 waves each 64x64.
// 3-buffer LDS pipeline + register double-buffered fragments (R5 form,
// best measured). LDS rows are 32 shorts (4 chunks of 16B); chunk position
// XOR-swizzled by (row&3)^(row>>2) on both store and read sides.
__device__ __forceinline__ void gemm_core(const short* __restrict__ A,
                                          const short* __restrict__ BT,
                                          int K, int bm0, int bn0,
                                          short* sm, f32x4 acc[4][4]) {
    const int tid = threadIdx.x;
    const int lane = tid & 63;
    const int w = tid >> 6;
    const int wr0 = (w >> 1) * 64;
    const int wc0 = (w & 1) * 64;
    const int l15 = lane & 15, quad = lane >> 4;
    const int sr = lane >> 2;                              // staging row in 16-row chunk
    const int slog = (lane & 3) ^ (sr & 3) ^ (sr >> 2);    // swizzled k-chunk to fetch

#pragma unroll
    for (int i = 0; i < 4; i++)
#pragma unroll
        for (int j = 0; j < 4; j++) acc[i][j] = (f32x4)0.f;

    const short* sp[4];
    int sdo[4];
#pragma unroll
    for (int i = 0; i < 4; i++) {
        int c = w * 4 + i;
        sp[i] = (c < 8) ? A + (size_t)(bm0 + c * 16 + sr) * K + slog * 8
                        : BT + (size_t)(bn0 + (c - 8) * 16 + sr) * K + slog * 8;
        sdo[i] = c * 512;
    }
    auto stage = [&](int buf) {
        short* bb = sm + buf * 8192;
#pragma unroll
        for (int i = 0; i < 4; i++) {
            gl2lds16(sp[i], bb + sdo[i]);
            sp[i] += 32;
        }
    };
    const int ph = (quad ^ (l15 & 3) ^ (l15 >> 2)) * 8;
    auto loadf = [&](bf16x8* af, bf16x8* bfr, int buf) {
        const short* Ab = sm + buf * 8192;
        const short* Bb = Ab + 4096;
#pragma unroll
        for (int im = 0; im < 4; im++)
            af[im] = *(const bf16x8*)&Ab[(wr0 + im * 16 + l15) * 32 + ph];
#pragma unroll
        for (int in = 0; in < 4; in++)
            bfr[in] = *(const bf16x8*)&Bb[(wc0 + in * 16 + l15) * 32 + ph];
        __builtin_amdgcn_sched_barrier(0);   // pin reads here (issue-early)
    };
    auto computef = [&](const bf16x8* af, const bf16x8* bfr) {
        __builtin_amdgcn_s_setprio(1);
#pragma unroll
        for (int im = 0; im < 4; im++)
#pragma unroll
            for (int in = 0; in < 4; in++)
                acc[im][in] = __builtin_amdgcn_mfma_f32_16x16x32_bf16(af[im], bfr[in], acc[im][in], 0, 0, 0);
        __builtin_amdgcn_s_setprio(0);
    };

    stage(0); stage(1);
    VMW(4);                                            // tile 0 resident
    __builtin_amdgcn_s_barrier();
    asm volatile("" ::: "memory");

    bf16x8 aA[4], bA[4], aB[4], bB[4];
    loadf(aA, bA, 0);

    const int nt = K >> 5;                 // 32 K-steps of 32
    int bs = 2, rb = 1;
    for (int t = 0; t < nt - 2; t += 2) {
        stage(bs); bs = (bs == 2) ? 0 : bs + 1;
        SYNC(4);                                   // tile t+1 resident
        loadf(aB, bB, rb); rb = (rb == 2) ? 0 : rb + 1;
        computef(aA, bA);                          // tile t
        stage(bs); bs = (bs == 2) ? 0 : bs + 1;
        SYNC(4);                                   // tile t+2 resident
        loadf(aA, bA, rb); rb = (rb == 2) ? 0 : rb + 1;
        computef(aB, bB);                          // tile t+1
    }
    SYNC(0);                                       // tile nt-1 resident
    loadf(aB, bB, rb);
    computef(aA, bA);                              // tile nt-2
    computef(aB, bB);                              // tile nt-1
}

// QKV projection.  grid (32, 8, 3).
__global__ __launch_bounds__(256, 3) void gemm_qkv(
    const short* __restrict__ xb,
    const short* __restrict__ wqT, const short* __restrict__ wkT, const short* __restrict__ wvT,
    const float* __restrict__ bq, const float* __restrict__ bk, const float* __restrict__ bv,
    unsigned short* __restrict__ qb, unsigned short* __restrict__ kb, unsigned short* __restrict__ vTb) {
    __shared__ short sm[24576];            // 3 x (A 4096 + B 4096) = 48KB
    const int z = blockIdx.z;
    const short* Amat = (z == 2) ? wvT : xb;
    const short* Bmat = (z == 0) ? wqT : (z == 1) ? wkT : xb;
    const float* bias = (z == 0) ? bq : (z == 1) ? bk : bv;
    const float scl = (z == 0) ? 0.125f * LOG2E : 1.f;
    const int bm0 = (z == 2) ? blockIdx.y * 128 : blockIdx.x * 128;
    const int bn0 = (z == 2) ? blockIdx.x * 128 : blockIdx.y * 128;
    f32x4 acc[4][4];
    gemm_core(Amat, Bmat, 1024, bm0, bn0, sm, acc);
    const int lane = threadIdx.x & 63, w = threadIdx.x >> 6;
    const int wr0 = (w >> 1) * 64, wc0 = (w & 1) * 64, l15 = lane & 15, quad = lane >> 4;
    if (z == 2) {
        for (int im = 0; im < 4; im++)
            for (int in = 0; in < 4; in++)
                for (int r = 0; r < 4; r++) {
                    int rowa = bm0 + wr0 + im * 16 + quad * 4 + r;   // h*64+a
                    int colg = bn0 + wc0 + in * 16 + l15;            // b*2048+s
                    unsigned short ov = f2bf(acc[im][in][r] + bias[rowa]);
                    int b = colg >> 11, s = colg & 2047;
                    vTb[(size_t)b * 2097152 + (size_t)rowa * 2048 + s] = ov;
                }
    } else {
        for (int im = 0; im < 4; im++)
            for (int in = 0; in < 4; in++)
                for (int r = 0; r < 4; r++) {
                    int rowg = bm0 + wr0 + im * 16 + quad * 4 + r;   // b*2048+s
                    int colg = bn0 + wc0 + in * 16 + l15;            // h*64+a
                    unsigned short ov = f2bf((acc[im][in][r] + bias[colg]) * scl);
                    int b = rowg >> 11, s = rowg & 2047;
                    int h = colg >> 6, a = colg & 63;
                    int bh = b * 16 + h;
                    if (z == 0) qb[((size_t)bh * 2048 + s) * 64 + a] = ov;
                    else        kb[((size_t)bh * 2048 + s) * 64 + a] = ov;
                }
    }
}

__global__ __launch_bounds__(256, 3) void gemm_out(
    const short* __restrict__ att, const short* __restrict__ woT,
    const float* __restrict__ bo, float* __restrict__ out) {
    __shared__ short sm[24576];
    const int bm0 = blockIdx.x * 128, bn0 = blockIdx.y * 128;
    f32x4 acc[4][4];
    gemm_core(att, woT, 1024, bm0, bn0, sm, acc);
    const int lane = threadIdx.x & 63, w = threadIdx.x >> 6;
    const int wr0 = (w >> 1) * 64, wc0 = (w & 1) * 64, l15 = lane & 15, quad = lane >> 4;
    for (int im = 0; im < 4; im++)
        for (int in = 0; in < 4; in++)
            for (int r = 0; r < 4; r++) {
                int rowg = bm0 + wr0 + im * 16 + quad * 4 + r;
                int colg = bn0 + wc0 + in * 16 + l15;
                out[(size_t)rowg * 1024 + colg] = acc[im][in][r] + bo[colg];
            }
}

// ---------------------------------------------------------------- flash attn
// 1D grid 512 (XCD-swizzled); 256 thr = 4 waves, each owns 32 q-cols.
// BKV=64, HD=64. S^T = K*Q^T, O^T = V^T*P^T; softmax w/o max-subtraction.
// T15 pipeline (PV deferred one tile); P in registers (cvt_pk + permlane).
//
// 2-STEP BARRIER CADENCE (this round): barrier only after even steps.
// Role-split staging FIFOs (waves 0-1 stage K only, 2-3 V only) make
// counted vmcnt per-role exact:  K lookahead 4 / 5 buffers, V lookahead
// 3 / 5 buffers (80KB LDS, 2 blocks/CU). At each barrier vmcnt(4) leaves
// only the newest stage in flight -> the 2-step window's reads
// {kf(2k+2),kf(2k+3),vf(2k+1),vf(2k+2)} are exactly resident, and the
// window itself runs with ZERO sync instructions (waves drift, LDS/VALU/
// MFMA phases interleave across waves instead of convoying).
// Overwrite safety (both parities): K stage(t+4) overwrites tile t-1 whose
// kf-read was at step t-2 <= last barrier; V stage(t+3) overwrites tile
// t-2 whose vf-read was at step t-2 <= last barrier. t=1 edge covered by
// the barrier after step 0 (drains the pre-loop kf(0) reads).
__global__ __launch_bounds__(256, 2) void flash_attn(
    const unsigned short* __restrict__ qb, const unsigned short* __restrict__ kb,
    const unsigned short* __restrict__ vTb, unsigned short* __restrict__ att) {
    __shared__ short Ks[5][4096];              // 40KB: 5 K tiles of 64x64
    __shared__ short Vs[5][4096];              // 40KB: 5 V tiles
    const int tid = threadIdx.x, lane = tid & 63, w = tid >> 6;
    const int l15 = lane & 15, quad = lane >> 4;
    const int lid = ((blockIdx.x & 7) << 6) | (blockIdx.x >> 3);   // XCD swizzle
    const int q0 = (lid & 15) * 128;
    const int bh = lid >> 4;
    const size_t qkbase = (size_t)bh * 2048 * 64;
    const size_t vbase = (size_t)bh * 64 * 2048;
    const int sr = lane >> 3;                  // staging row (8 rows / 1KB call)
    const int slog = (lane & 7) ^ sr;          // swizzled chunk to fetch
    const int l7 = l15 & 7;
    const bool isv = (w >= 2);

    // per-wave staging: waves 0-1 own K rows (32 each), waves 2-3 own V rows
    const unsigned short* sgp;
    int sgstep, sgr;
    short* sgb;
    if (!isv) {
        sgp = kb + qkbase + (size_t)(w * 32 + sr) * 64 + slog * 8;
        sgstep = 4096; sgr = 512;
        sgb = &Ks[0][0] + w * 2048;
    } else {
        sgp = vTb + vbase + (size_t)((w - 2) * 32 + sr) * 2048 + slog * 8;
        sgstep = 64; sgr = 16384;
        sgb = &Vs[0][0] + (w - 2) * 2048;
    }
    auto stage_tile = [&](int bufK, int bufV) {   // 4 gl2lds per wave per tile
        short* sd = sgb + (isv ? bufV : bufK) * 4096;
        gl2lds16(sgp, sd);
        gl2lds16(sgp + sgr, sd + 512);
        gl2lds16(sgp + 2 * sgr, sd + 1024);
        gl2lds16(sgp + 3 * sgr, sd + 1536);
        sgp += sgstep;
    };

    const int wq0 = w * 32;
    const int c0 = (quad ^ l7) * 8, c1 = c0 ^ 32;   // swizzled d-chunk offsets (LDS)
    const int fb = l15 * 64;                        // fragment row base

    // Q fragments direct from global (B-operand layout: row=l15, k=quad*8+j)
    const unsigned short* qrow = qb + qkbase + (size_t)(q0 + wq0 + l15) * 64 + quad * 8;
    bf16x8 aq00 = *(const bf16x8*)qrow;
    bf16x8 aq01 = *(const bf16x8*)(qrow + 32);
    bf16x8 aq10 = *(const bf16x8*)(qrow + 1024);
    bf16x8 aq11 = *(const bf16x8*)(qrow + 1024 + 32);

    // prologue: K tiles 0-3 (lookahead 4), V tiles 0-2 (lookahead 3)
    stage_tile(0, 0); stage_tile(1, 1); stage_tile(2, 2);
    if (!isv) stage_tile(3, 3);
    VMW(4);                     // K: 0-2 resident (K3 in flight); V: 0-1 (V2 in flight)
    __builtin_amdgcn_s_barrier();
    asm volatile("" ::: "memory");

    f32x4 o0[4], o1[4];
#pragma unroll
    for (int dt = 0; dt < 4; dt++) { o0[dt] = (f32x4)0.f; o1[dt] = (f32x4)0.f; }
    f32x4 ls0 = (f32x4)0.f, ls1 = (f32x4)0.f;

    auto load_kf = [&](bf16x8* kf, int buf) {
        const short* Kb = &Ks[0][0] + buf * 4096;
#pragma unroll
        for (int t = 0; t < 4; t++) {
            kf[2 * t]     = *(const bf16x8*)(Kb + fb + c0 + t * 1024);
            kf[2 * t + 1] = *(const bf16x8*)(Kb + fb + c1 + t * 1024);
        }
    };
    bf16x8 vf[8];                                    // single V bank
    auto load_vf = [&](int buf) {
        const short* Vb = &Vs[0][0] + buf * 4096;
#pragma unroll
        for (int t = 0; t < 4; t++) {
            vf[2 * t]     = *(const bf16x8*)(Vb + fb + c0 + t * 1024);
            vf[2 * t + 1] = *(const bf16x8*)(Vb + fb + c1 + t * 1024);
        }
    };

    auto qk = [&](const bf16x8* kf, f32x4* sc0, f32x4* sc1) {
        __builtin_amdgcn_s_setprio(1);
#pragma unroll
        for (int t = 0; t < 4; t++) {
            sc0[t] = __builtin_amdgcn_mfma_f32_16x16x32_bf16(kf[2 * t], aq00, (f32x4)0.f, 0, 0, 0);
            sc1[t] = __builtin_amdgcn_mfma_f32_16x16x32_bf16(kf[2 * t], aq10, (f32x4)0.f, 0, 0, 0);
        }
#pragma unroll
        for (int t = 0; t < 4; t++) {
            sc0[t] = __builtin_amdgcn_mfma_f32_16x16x32_bf16(kf[2 * t + 1], aq01, sc0[t], 0, 0, 0);
            sc1[t] = __builtin_amdgcn_mfma_f32_16x16x32_bf16(kf[2 * t + 1], aq11, sc1[t], 0, 0, 0);
        }
        __builtin_amdgcn_s_setprio(0);
    };

    // exp2 + row-sum + in-register P transpose (C-frag -> PV B-frag)
    auto smax = [&](f32x4 (&sc)[4], f32x4& lsr, bf16x8* bp) {
#pragma unroll
        for (int t = 0; t < 4; t++) {
#pragma unroll
            for (int r = 0; r < 4; r++) sc[t][r] = __ocml_native_exp2_f32(sc[t][r]);
            lsr += sc[t];
        }
#pragma unroll
        for (int t2 = 0; t2 < 2; t2++) {
            unsigned pa = pk_bf16(sc[2 * t2][0], sc[2 * t2][1]);
            unsigned pb = pk_bf16(sc[2 * t2][2], sc[2 * t2][3]);
            unsigned pc = pk_bf16(sc[2 * t2 + 1][0], sc[2 * t2 + 1][1]);
            unsigned pd = pk_bf16(sc[2 * t2 + 1][2], sc[2 * t2 + 1][3]);
            asm("v_permlane32_swap_b32 %0, %1" : "+v"(pa), "+v"(pc));
            asm("v_permlane32_swap_b32 %0, %1" : "+v"(pb), "+v"(pd));
            asm("v_permlane16_swap_b32 %0, %1" : "+v"(pa), "+v"(pc));
            asm("v_permlane16_swap_b32 %0, %1" : "+v"(pb), "+v"(pd));
            union { unsigned u[4]; bf16x8 v; } cvt;
            cvt.u[0] = pa; cvt.u[1] = pb; cvt.u[2] = pc; cvt.u[3] = pd;
            bp[t2] = cvt.v;
        }
    };

    auto pv = [&](const bf16x8* bp) {       // PV from bp bank + current vf
        __builtin_amdgcn_s_setprio(1);
#pragma unroll
        for (int t2 = 0; t2 < 2; t2++)
#pragma unroll
            for (int dt = 0; dt < 4; dt++) {
                o0[dt] = __builtin_amdgcn_mfma_f32_16x16x32_bf16(vf[2 * dt + t2], bp[t2], o0[dt], 0, 0, 0);
                o1[dt] = __builtin_amdgcn_mfma_f32_16x16x32_bf16(vf[2 * dt + t2], bp[2 + t2], o1[dt], 0, 0, 0);
            }
        __builtin_amdgcn_s_setprio(0);
    };

    bf16x8 kfA[8], kfB[8];
    bf16x8 bpA[4], bpB[4];

    load_kf(kfA, 0);
    asm volatile("s_waitcnt lgkmcnt(0)" ::: "memory");
    __builtin_amdgcn_sched_barrier(0);

    // step t: kfC = frags(t), kfN <- tile t+1 (buf nbuf), bpC <- bp(t),
    // PV(t-1) from bpP + vf (holding tile t-1), then vf <- tile t (vbuf).
    // stmode: 0 = no stage, 1 = both roles stage, 2 = V-waves only.
    auto step = [&](int nbuf, int vbuf, const bf16x8* kfC, bf16x8* kfN,
                    bf16x8* bpC, const bf16x8* bpP, bool dokf, bool dopv,
                    int stmode, int sk, int sv) {
        if (dokf) load_kf(kfN, nbuf);
        __builtin_amdgcn_sched_barrier(0);   // pin kf reads early (hide latency)
        f32x4 sc0[4], sc1[4];
        qk(kfC, sc0, sc1);
        smax(sc0, ls0, bpC);
        smax(sc1, ls1, bpC + 2);
        if (dopv) pv(bpP);
        load_vf(vbuf);                       // after PV consumed vf(t-1)
        if (stmode == 1 || (stmode == 2 && isv)) stage_tile(sk, sv);
    };

    // buffer counters: bkf=(t+1)%5, bvf=t%5, bsk=(t+4)%5 (K stage),
    // bsv=(t+3)%5 (V stage)
    int bkf = 1, bvf = 0, bsk = 4, bsv = 3;
    auto adv = [&] {
        bkf = (bkf == 4) ? 0 : bkf + 1;
        bvf = (bvf == 4) ? 0 : bvf + 1;
        bsk = (bsk == 4) ? 0 : bsk + 1;
        bsv = (bsv == 4) ? 0 : bsv + 1;
    };

    // t = 0
    step(bkf, bvf, kfA, kfB, bpA, bpB, true, false, 1, bsk, bsv); adv();
    SYNC(4);
    for (int k = 0; k < 13; k++) {            // windows (1,2) .. (25,26)
        step(bkf, bvf, kfB, kfA, bpB, bpA, true, true, 1, bsk, bsv); adv();
        step(bkf, bvf, kfA, kfB, bpA, bpB, true, true, 1, bsk, bsv); adv();
        SYNC(4);
    }
    // t = 27 (stage K31 + V30), t = 28 (stage V31 only)
    step(bkf, bvf, kfB, kfA, bpB, bpA, true, true, 1, bsk, bsv); adv();
    step(bkf, bvf, kfA, kfB, bpA, bpB, true, true, 2, bsk, bsv); adv();
    SYNC(0);                                  // everything resident
    // t = 29, 30, 31 (no staging, no barriers needed)
    step(bkf, bvf, kfB, kfA, bpB, bpA, true, true, 0, 0, 0); adv();
    step(bkf, bvf, kfA, kfB, bpA, bpB, true, true, 0, 0, 0); adv();
    step(bkf, bvf, kfB, kfA, bpB, bpA, false, true, 0, 0, 0);
    asm volatile("s_waitcnt lgkmcnt(0)" ::: "memory");   // vf(31) landed
    pv(bpB);                                             // final PV(31)

    const int b = bh >> 4, h = bh & 15;
    float l0 = (ls0[0] + ls0[1]) + (ls0[2] + ls0[3]);
    l0 += __shfl_xor(l0, 16);
    l0 += __shfl_xor(l0, 32);
    float inv0 = 1.f / l0;
    float l1 = (ls1[0] + ls1[1]) + (ls1[2] + ls1[3]);
    l1 += __shfl_xor(l1, 16);
    l1 += __shfl_xor(l1, 32);
    float inv1 = 1.f / l1;
    int s = q0 + wq0 + l15;
#pragma unroll
    for (int dt = 0; dt < 4; dt++) {
        int col = h * 64 + dt * 16 + quad * 4;
        uint2 pk;
        pk.x = pk_bf16(o0[dt][0] * inv0, o0[dt][1] * inv0);
        pk.y = pk_bf16(o0[dt][2] * inv0, o0[dt][3] * inv0);
        *(uint2*)&att[((size_t)b * 2048 + s) * 1024 + col] = pk;
        pk.x = pk_bf16(o1[dt][0] * inv1, o1[dt][1] * inv1);
        pk.y = pk_bf16(o1[dt][2] * inv1, o1[dt][3] * inv1);
        *(uint2*)&att[((size_t)b * 2048 + s + 16) * 1024 + col] = pk;
    }
}

extern "C" void kernel_launch(void* const* d_in, const int* in_sizes, int n_in,
                              void* d_out, int out_size, void* d_ws, size_t ws_size,
                              hipStream_t stream) {
    const float* x  = (const float*)d_in[0];
    const float* Wq = (const float*)d_in[1];
    const float* bq = (const float*)d_in[2];
    const float* Wk = (const float*)d_in[3];
    const float* bk = (const float*)d_in[4];
    const float* Wv = (const float*)d_in[5];
    const float* bv = (const float*)d_in[6];
    const float* Wo = (const float*)d_in[7];
    const float* bo = (const float*)d_in[8];
    float* out = (float*)d_out;

    short* ws  = (short*)d_ws;
    short* xb  = ws;                          // 4M shorts
    short* wqT = ws + 4 * 1024 * 1024;        // 1M each
    short* wkT = wqT + 1024 * 1024;
    short* wvT = wkT + 1024 * 1024;
    short* woT = wvT + 1024 * 1024;
    short* qb  = woT + 1024 * 1024;           // 4M each
    short* kb  = qb + 4 * 1024 * 1024;
    short* vTb = kb + 4 * 1024 * 1024;
    short* att = vTb + 4 * 1024 * 1024;       // total 24M shorts = 48MB

    prep<<<8192, 256, 0, stream>>>(x, Wq, Wk, Wv, Wo, (unsigned int*)xb,
                                   (unsigned short*)wqT, (unsigned short*)wkT,
                                   (unsigned short*)wvT, (unsigned short*)woT);
    gemm_qkv<<<dim3(32, 8, 3), 256, 0, stream>>>(xb, wqT, wkT, wvT, bq, bk, bv,
                                                 (unsigned short*)qb, (unsigned short*)kb,
                                                 (unsigned short*)vTb);
    flash_attn<<<512, 256, 0, stream>>>((const unsigned short*)qb,
                                        (const unsigned short*)kb,
                                        (const unsigned short*)vTb,
                                        (unsigned short*)att);
    gemm_out<<<dim3(32, 8), 256, 0, stream>>>(att, woT, bo, out);
}